// Round 1
// 683.417 us; speedup vs baseline: 1.7747x; 1.7747x over previous
//
#include <hip/hip_runtime.h>
#include <hip/hip_bf16.h>

#define B_ 2
#define S_ 2048
#define HID_ 1536
#define H_ 12
#define HD_ 128
#define LAT_ 192
#define LATP_ 256          // LAT padded to 128-multiple for MFMA tiles
#define ROT_ 64
#define M_ (B_*S_)         // 4096

typedef __hip_bfloat16 bf16;

using short8  = __attribute__((ext_vector_type(8))) short;
using short4v = __attribute__((ext_vector_type(4))) short;
using float4v = __attribute__((ext_vector_type(4))) float;

__device__ __forceinline__ unsigned short f2bf(float f) {
  __hip_bfloat16 h = __float2bfloat16(f);
  unsigned short u; __builtin_memcpy(&u, &h, 2); return u;
}

// async global->LDS, 16B per lane (wave-uniform LDS base + lane*16)
#define GLDS16(gp, lp) __builtin_amdgcn_global_load_lds( \
    (__attribute__((address_space(1))) void*)(size_t)(gp), \
    (__attribute__((address_space(3))) void*)(lp), 16, 0, 0)

__global__ __launch_bounds__(256)
void fillf_k(float* __restrict__ out, float v, int n)
{
  int i = blockIdx.x*256 + threadIdx.x;
  if (i < n) out[i] = v;
}

// ---------------------------------------------------------------------------
// fp32 -> bf16 elementwise pack (n multiple of 1024)
// ---------------------------------------------------------------------------
__global__ __launch_bounds__(256)
void packA_k(const float* __restrict__ in, bf16* __restrict__ out)
{
  int i = (blockIdx.x*256 + threadIdx.x)*4;
  float4 v = *(const float4*)&in[i];
  short4v o;
  o[0] = (short)f2bf(v.x); o[1] = (short)f2bf(v.y);
  o[2] = (short)f2bf(v.z); o[3] = (short)f2bf(v.w);
  *(short4v*)&out[i] = o;
}

// ---------------------------------------------------------------------------
// Weight transpose+pack: W(K,N) fp32 -> Wt(Np,K) bf16, zero-pad rows n>=Nn.
// grid = (Kn/32, Np/32), 256 threads, LDS 32x33 tile.
// ---------------------------------------------------------------------------
__global__ __launch_bounds__(256)
void packT_k(const float* __restrict__ W, bf16* __restrict__ Wt,
             int Kn, int Nn)
{
  __shared__ float t[32][33];
  const int kb = blockIdx.x*32, nb = blockIdx.y*32;
  const int tx = threadIdx.x & 31, ty = threadIdx.x >> 5;
  #pragma unroll
  for (int i = 0; i < 4; i++) {
    int n = nb + tx;
    t[ty+8*i][tx] = (n < Nn) ? W[(size_t)(kb+ty+8*i)*Nn + n] : 0.f;
  }
  __syncthreads();
  #pragma unroll
  for (int i = 0; i < 4; i++) {
    int n = nb + ty + 8*i;
    Wt[(size_t)n*Kn + kb + tx] = __float2bfloat16(t[tx][ty+8*i]);
  }
}

// ---------------------------------------------------------------------------
// MFMA bf16 GEMM, m97 structure: C(M,N) = A(M,K) @ Bt(N,K)^T.
// 128x128 tile, BK=32, 4 waves in 2x2, each wave 64x64 (4x4 of 16x16x32).
// A,Bt bf16 row-major; LDS staged linearly via global_load_lds dwordx4.
// Layouts (verified m89/m120): A frag [m=lane&15][k=quad*8+j];
// B frag from Bt[n=lane&15][k=quad*8+j]; C/D col=lane&15,row=quad*4+r.
// M,N must be multiples of 128; K multiple of 32 (shapes padded upstream).
// ---------------------------------------------------------------------------
template<int CBF>
__global__ __launch_bounds__(256)
void gemm_mfma(const bf16* __restrict__ A, const bf16* __restrict__ Bt,
               void* __restrict__ Cv, int Kn, int lda, int ldb, int ldc)
{
  __shared__ bf16 As[128*32];   // [m][k], 8 KB
  __shared__ bf16 Bs[128*32];   // [n][k], 8 KB

  const int tid  = threadIdx.x;
  const int lane = tid & 63;
  const int w    = tid >> 6;
  const int col  = lane & 15, quad = lane >> 4;
  const int wr   = w >> 1, wc = w & 1;
  const size_t m0 = (size_t)blockIdx.y * 128;
  const size_t n0 = (size_t)blockIdx.x * 128;

  const int r0 = tid >> 2, seg = tid & 3;          // 4 chunks of 8 bf16 per row
  const bf16* Ag0 = A  + (m0 + r0)*lda + seg*8;
  const bf16* Ag1 = Ag0 + (size_t)64*lda;
  const bf16* Bg0 = Bt + (n0 + r0)*ldb + seg*8;
  const bf16* Bg1 = Bg0 + (size_t)64*ldb;

  float4v acc[4][4];
  #pragma unroll
  for (int i=0;i<4;i++)
    #pragma unroll
    for (int j=0;j<4;j++) acc[i][j] = (float4v){0.f,0.f,0.f,0.f};

  for (int k0 = 0; k0 < Kn; k0 += 32) {
    GLDS16(Ag0 + k0, As + tid*8);
    GLDS16(Ag1 + k0, As + (tid+256)*8);
    GLDS16(Bg0 + k0, Bs + tid*8);
    GLDS16(Bg1 + k0, Bs + (tid+256)*8);
    __syncthreads();                 // drains vmcnt: LDS tiles ready

    short8 af[4], bfr[4];
    #pragma unroll
    for (int i=0;i<4;i++)
      af[i]  = *(const short8*)&As[(wr*64 + i*16 + col)*32 + quad*8];
    #pragma unroll
    for (int j=0;j<4;j++)
      bfr[j] = *(const short8*)&Bs[(wc*64 + j*16 + col)*32 + quad*8];

    #pragma unroll
    for (int i=0;i<4;i++)
      #pragma unroll
      for (int j=0;j<4;j++)
        acc[i][j] = __builtin_amdgcn_mfma_f32_16x16x32_bf16(af[i], bfr[j], acc[i][j], 0,0,0);
    __syncthreads();
  }

  #pragma unroll
  for (int i=0;i<4;i++) {
    const size_t row0 = m0 + wr*64 + i*16 + quad*4;
    #pragma unroll
    for (int j=0;j<4;j++) {
      const size_t c = n0 + wc*64 + j*16 + col;
      #pragma unroll
      for (int r=0;r<4;r++) {
        if (CBF) ((bf16*)Cv)[(row0+r)*ldc + c] = __float2bfloat16(acc[i][j][r]);
        else     ((float*)Cv)[(row0+r)*ldc + c] = acc[i][j][r];
      }
    }
  }
}

// ---------------------------------------------------------------------------
// Standalone rope, in-place on the flat (M, 768) k_r and q_r buffers.
// ---------------------------------------------------------------------------
__global__ __launch_bounds__(256)
void rope_k(float* __restrict__ kr, float* __restrict__ qr,
            const float* __restrict__ emb)
{
  int idx = blockIdx.x*256 + threadIdx.x;
  int i = idx & 31;
  int hm = idx >> 5;
  int h = hm % H_, m = hm / H_;
  int s = m % S_;
  float sn = emb[(size_t)s*ROT_ + i];
  float cs = emb[(size_t)s*ROT_ + 32 + i];

  float* r1 = kr + (size_t)m*(H_*ROT_) + h*ROT_;
  float x1 = r1[i], x2 = r1[32+i];
  r1[i]    = x1*cs - x2*sn;
  r1[32+i] = x1*sn + x2*cs;

  float* r2 = qr + (size_t)m*(H_*ROT_) + h*ROT_;
  x1 = r2[i]; x2 = r2[32+i];
  r2[i]    = x1*cs - x2*sn;
  r2[32+i] = x1*sn + x2*cs;
}

// ---------------------------------------------------------------------------
// MFMA flash attention, causal. Block = 4 waves = 64 queries; 32-key blocks.
// Unchanged from verified kernel except blockIdx remap: heaviest query tiles
// (largest qt, work ∝ qt+1) launch FIRST to kill the load-imbalance tail.
// ---------------------------------------------------------------------------
#define KSTR 136
#define VSTR 44
#define PSTR 44

__global__ __launch_bounds__(256)
void attn_mfma(const float* __restrict__ qc, const float* __restrict__ qr,
               const float* __restrict__ kc, const float* __restrict__ kr,
               const bf16* __restrict__ vfl, bf16* __restrict__ at)
{
  const int qt = (S_/64 - 1) - (blockIdx.x / (B_*H_));   // long-first
  const int bh = blockIdx.x % (B_*H_);
  const int h  = bh % H_, b = bh / H_;
  const int tid  = threadIdx.x;
  const int w    = tid >> 6;
  const int lane = tid & 63;
  const int col  = lane & 15;
  const int quad = lane >> 4;

  __shared__ unsigned short Ks[32*KSTR];        // 8704 B
  __shared__ unsigned short Vt[128*VSTR];       // 11264 B
  __shared__ unsigned short Ps[4][16*PSTR];     // 5632 B

  const int q0  = qt * 64;
  const int q0w = q0 + w*16;

  short8 qf[4];
  {
    const size_t mrow = (size_t)b*S_ + q0w + col;
    const float* qh0 = qc + mrow*(H_*ROT_) + h*ROT_;
    const float* qh1 = qr + mrow*(H_*ROT_) + h*ROT_;
    #pragma unroll
    for (int kk = 0; kk < 4; kk++) {
      const float* src = (kk < 2 ? qh0 + kk*32 : qh1 + (kk-2)*32) + quad*8;
      short8 v;
      #pragma unroll
      for (int j = 0; j < 8; j++) v[j] = (short)f2bf(src[j]);
      qf[kk] = v;
    }
  }

  float4v O[8];
  #pragma unroll
  for (int t=0;t<8;t++) O[t] = (float4v){0.f,0.f,0.f,0.f};
  float mrow[4], lrow[4];
  #pragma unroll
  for (int r=0;r<4;r++){ mrow[r] = -1e30f; lrow[r] = 0.f; }

  const float scale = 0.08838834764831845f;   // 1/sqrt(128)
  const int nkb = 2*(qt+1);

  for (int kb = 0; kb < nkb; kb++) {
    const int k0 = kb * 32;

    for (int p = tid; p < 32*64; p += 256) {
      int key = p >> 6, j = p & 63;
      size_t mk = (size_t)b*S_ + k0 + key;
      const float* src = (j < 32) ? (kc + mk*(H_*ROT_) + h*ROT_ + 2*j)
                                  : (kr + mk*(H_*ROT_) + h*ROT_ + 2*j - 64);
      unsigned int packed = (unsigned int)f2bf(src[0]) |
                            ((unsigned int)f2bf(src[1]) << 16);
      *(unsigned int*)&Ks[key*KSTR + 2*j] = packed;
    }
    for (int p = tid; p < 128*16; p += 256) {
      int d = p >> 4, kp = (p & 15)*2;
      const unsigned short* vr = (const unsigned short*)vfl;
      size_t base = ((size_t)b*S_ + k0 + kp)*HID_ + h*HD_ + d;
      unsigned int packed = (unsigned int)vr[base] |
                            ((unsigned int)vr[base + HID_] << 16);
      *(unsigned int*)&Vt[d*VSTR + kp] = packed;
    }
    __syncthreads();

    if (k0 <= q0w + 15) {
      float4v Sf0 = (float4v){0,0,0,0}, Sf1 = (float4v){0,0,0,0};
      #pragma unroll
      for (int kk = 0; kk < 4; kk++) {
        short8 b0 = *(const short8*)&Ks[ col      *KSTR + 32*kk + quad*8];
        short8 b1 = *(const short8*)&Ks[(col+16)  *KSTR + 32*kk + quad*8];
        Sf0 = __builtin_amdgcn_mfma_f32_16x16x32_bf16(qf[kk], b0, Sf0, 0,0,0);
        Sf1 = __builtin_amdgcn_mfma_f32_16x16x32_bf16(qf[kk], b1, Sf1, 0,0,0);
      }

      float al[4];
      #pragma unroll
      for (int r = 0; r < 4; r++) {
        const int qpos = q0w + quad*4 + r;
        float s0 = Sf0[r] * scale; if (k0 + col      > qpos) s0 = -1e30f;
        float s1 = Sf1[r] * scale; if (k0 + 16 + col > qpos) s1 = -1e30f;
        float mt = fmaxf(s0, s1);
        #pragma unroll
        for (int off = 8; off >= 1; off >>= 1)
          mt = fmaxf(mt, __shfl_xor(mt, off));
        float mnew = fmaxf(mrow[r], mt);
        float p0 = __expf(s0 - mnew);
        float p1 = __expf(s1 - mnew);
        float lt = p0 + p1;
        #pragma unroll
        for (int off = 8; off >= 1; off >>= 1)
          lt += __shfl_xor(lt, off);
        al[r] = __expf(mrow[r] - mnew);
        lrow[r] = lrow[r]*al[r] + lt;
        mrow[r] = mnew;
        const int prow = quad*4 + r;
        Ps[w][prow*PSTR + col]      = f2bf(p0);
        Ps[w][prow*PSTR + col + 16] = f2bf(p1);
      }
      #pragma unroll
      for (int t = 0; t < 8; t++)
        #pragma unroll
        for (int r = 0; r < 4; r++) O[t][r] *= al[r];

      short4v pa = *(const short4v*)&Ps[w][col*PSTR + quad*8];
      short4v pb = *(const short4v*)&Ps[w][col*PSTR + quad*8 + 4];
      short8 pf;
      #pragma unroll
      for (int j=0;j<4;j++){ pf[j] = pa[j]; pf[j+4] = pb[j]; }
      #pragma unroll
      for (int t = 0; t < 8; t++) {
        const unsigned short* vp = &Vt[(16*t + col)*VSTR + quad*8];
        short4v va = *(const short4v*)vp;
        short4v vb = *(const short4v*)(vp + 4);
        short8 vf;
        #pragma unroll
        for (int j=0;j<4;j++){ vf[j] = va[j]; vf[j+4] = vb[j]; }
        O[t] = __builtin_amdgcn_mfma_f32_16x16x32_bf16(pf, vf, O[t], 0,0,0);
      }
    }
    __syncthreads();
  }

  #pragma unroll
  for (int r = 0; r < 4; r++) {
    const float linv = 1.f / lrow[r];
    const size_t mq = (size_t)b*S_ + q0w + quad*4 + r;
    bf16* dst = at + mq*HID_ + h*HD_ + col;
    #pragma unroll
    for (int t = 0; t < 8; t++)
      dst[16*t] = __float2bfloat16(O[t][r] * linv);
  }
}

extern "C" void kernel_launch(void* const* d_in, const int* in_sizes, int n_in,
                              void* d_out, int out_size, void* d_ws, size_t ws_size,
                              hipStream_t stream)
{
  float* out = (float*)d_out;

  // Size guard tripwire.
  static const int sz_dict[10] = {6291456,131072,294912,294912,147456,
                                  147456,294912,1179648,147456,2359296};
  int bad = -1;
  if (n_in < 10) bad = 15;
  else {
    for (int i = 0; i < 10; i++)
      if (in_sizes[i] != sz_dict[i]) { bad = i; break; }
  }
  if (bad >= 0) {
    float v = 1.0e6f * (float)(1 + bad);
    if (bad < 10) v += (float)(in_sizes[bad] % 1000000);
    fillf_k<<<(out_size + 255)/256, 256, 0, stream>>>(out, v, out_size);
    return;
  }

  const float* hidden = (const float*)d_in[0];
  const float* emb    = (const float*)d_in[1];
  const float* Wkvd   = (const float*)d_in[2];
  const float* Wqd    = (const float*)d_in[3];
  const float* Wku    = (const float*)d_in[4];
  const float* Wqu    = (const float*)d_in[5];
  const float* Wvu    = (const float*)d_in[6];
  const float* Wrk    = (const float*)d_in[7];
  const float* Wrq    = (const float*)d_in[8];
  const float* Wo     = (const float*)d_in[9];

  // --- workspace carve (256B aligned each) ---
  char* wp = (char*)d_ws;
  size_t used = 0;
  auto alloc = [&](size_t bytes) -> void* {
    void* p = wp + used;
    used += (bytes + 255) & ~(size_t)255;
    return p;
  };
  bf16* hb   = (bf16*)alloc((size_t)M_*HID_*2);        // hidden bf16
  bf16* kvd  = (bf16*)alloc((size_t)M_*LATP_*2);       // (M,256) bf16, pad cols 0
  bf16* qd   = (bf16*)alloc((size_t)M_*LATP_*2);
  float* kc  = (float*)alloc((size_t)M_*(H_*ROT_)*4);  // (M,768) fp32
  float* qc  = (float*)alloc((size_t)M_*(H_*ROT_)*4);
  float* krr = (float*)alloc((size_t)M_*(H_*ROT_)*4);
  float* qrr = (float*)alloc((size_t)M_*(H_*ROT_)*4);
  bf16* vfl  = (bf16*)alloc((size_t)M_*HID_*2);        // (M,1536) bf16
  bf16* at   = (bf16*)alloc((size_t)M_*HID_*2);
  bf16* WkvdT= (bf16*)alloc((size_t)LATP_*HID_*2);     // (256,1536)
  bf16* WqdT = (bf16*)alloc((size_t)LATP_*HID_*2);
  bf16* WkuT = (bf16*)alloc((size_t)(H_*ROT_)*LAT_*2); // (768,192)
  bf16* WquT = (bf16*)alloc((size_t)(H_*ROT_)*LAT_*2);
  bf16* WvuT = (bf16*)alloc((size_t)HID_*LAT_*2);      // (1536,192)
  bf16* WrkT = (bf16*)alloc((size_t)(H_*ROT_)*HID_*2); // (768,1536)
  bf16* WrqT = (bf16*)alloc((size_t)(H_*ROT_)*LAT_*2);
  bf16* WoT  = (bf16*)alloc((size_t)HID_*HID_*2);      // (1536,1536)

  if (used > ws_size) {   // workspace tripwire
    fillf_k<<<(out_size + 255)/256, 256, 0, stream>>>(out, 5.0e7f, out_size);
    return;
  }

  // --- packs (depend only on inputs) ---
  packA_k<<<(M_*HID_)/1024, 256, 0, stream>>>(hidden, hb);
  packT_k<<<dim3(HID_/32, LATP_/32),    256, 0, stream>>>(Wkvd, WkvdT, HID_, LAT_);
  packT_k<<<dim3(HID_/32, LATP_/32),    256, 0, stream>>>(Wqd,  WqdT,  HID_, LAT_);
  packT_k<<<dim3(LAT_/32, (H_*ROT_)/32),256, 0, stream>>>(Wku,  WkuT,  LAT_, H_*ROT_);
  packT_k<<<dim3(LAT_/32, (H_*ROT_)/32),256, 0, stream>>>(Wqu,  WquT,  LAT_, H_*ROT_);
  packT_k<<<dim3(LAT_/32, HID_/32),     256, 0, stream>>>(Wvu,  WvuT,  LAT_, HID_);
  packT_k<<<dim3(HID_/32, (H_*ROT_)/32),256, 0, stream>>>(Wrk,  WrkT,  HID_, H_*ROT_);
  packT_k<<<dim3(LAT_/32, (H_*ROT_)/32),256, 0, stream>>>(Wrq,  WrqT,  LAT_, H_*ROT_);
  packT_k<<<dim3(HID_/32, HID_/32),     256, 0, stream>>>(Wo,   WoT,   HID_, HID_);

  // --- MFMA projection GEMMs: C = A @ Bt^T ---
  gemm_mfma<1><<<dim3(LATP_/128,     M_/128), 256, 0, stream>>>(hb,  WkvdT, kvd, HID_, HID_,  HID_, LATP_);
  gemm_mfma<1><<<dim3(LATP_/128,     M_/128), 256, 0, stream>>>(hb,  WqdT,  qd,  HID_, HID_,  HID_, LATP_);
  gemm_mfma<0><<<dim3((H_*ROT_)/128, M_/128), 256, 0, stream>>>(kvd, WkuT,  kc,  LAT_, LATP_, LAT_, H_*ROT_);
  gemm_mfma<0><<<dim3((H_*ROT_)/128, M_/128), 256, 0, stream>>>(qd,  WquT,  qc,  LAT_, LATP_, LAT_, H_*ROT_);
  gemm_mfma<1><<<dim3(HID_/128,      M_/128), 256, 0, stream>>>(kvd, WvuT,  vfl, LAT_, LATP_, LAT_, HID_);
  gemm_mfma<0><<<dim3((H_*ROT_)/128, M_/128), 256, 0, stream>>>(hb,  WrkT,  krr, HID_, HID_,  HID_, H_*ROT_);
  gemm_mfma<0><<<dim3((H_*ROT_)/128, M_/128), 256, 0, stream>>>(qd,  WrqT,  qrr, LAT_, LATP_, LAT_, H_*ROT_);

  rope_k<<<(M_*H_*32)/256, 256, 0, stream>>>(krr, qrr, emb);

  attn_mfma<<<B_*H_*(S_/64), 256, 0, stream>>>(qc, qrr, kc, krr, vfl, at);

  gemm_mfma<0><<<dim3(HID_/128, M_/128), 256, 0, stream>>>(at, WoT, out, HID_, HID_, HID_, HID_);
}

// Round 2
// 349.230 us; speedup vs baseline: 3.4729x; 1.9569x over previous
//
#include <hip/hip_runtime.h>
#include <hip/hip_bf16.h>

#define B_ 2
#define S_ 2048
#define HID_ 1536
#define H_ 12
#define HD_ 128
#define LAT_ 192
#define LATP_ 256
#define ROT_ 64
#define M_ (B_*S_)         // 4096

typedef __hip_bfloat16 bf16;

using short8  = __attribute__((ext_vector_type(8))) short;
using short4v = __attribute__((ext_vector_type(4))) short;
using float4v = __attribute__((ext_vector_type(4))) float;

__device__ __forceinline__ unsigned short f2bf(float f) {
  __hip_bfloat16 h = __float2bfloat16(f);
  unsigned short u; __builtin_memcpy(&u, &h, 2); return u;
}

// async global->LDS, 16B per lane (wave-uniform LDS base + lane*16)
#define GLDS16(gp, lp) __builtin_amdgcn_global_load_lds( \
    (__attribute__((address_space(1))) void*)(size_t)(gp), \
    (__attribute__((address_space(3))) void*)(lp), 16, 0, 0)

__global__ __launch_bounds__(256)
void fillf_k(float* __restrict__ out, float v, int n)
{
  int i = blockIdx.x*256 + threadIdx.x;
  if (i < n) out[i] = v;
}

// ---------------------------------------------------------------------------
// fp32 -> bf16 elementwise pack (n multiple of 1024)
// ---------------------------------------------------------------------------
__global__ __launch_bounds__(256)
void packA_k(const float* __restrict__ in, bf16* __restrict__ out)
{
  int i = (blockIdx.x*256 + threadIdx.x)*4;
  float4 v = *(const float4*)&in[i];
  short4v o;
  o[0] = (short)f2bf(v.x); o[1] = (short)f2bf(v.y);
  o[2] = (short)f2bf(v.z); o[3] = (short)f2bf(v.w);
  *(short4v*)&out[i] = o;
}

// ---------------------------------------------------------------------------
// Weight transpose+pack: W(K,N) fp32 -> Wt(Np,K) bf16, zero-pad rows n>=Nn.
// grid = (Kn/32, Np/32), 256 threads, LDS 32x33 tile.
// ---------------------------------------------------------------------------
__global__ __launch_bounds__(256)
void packT_k(const float* __restrict__ W, bf16* __restrict__ Wt,
             int Kn, int Nn)
{
  __shared__ float t[32][33];
  const int kb = blockIdx.x*32, nb = blockIdx.y*32;
  const int tx = threadIdx.x & 31, ty = threadIdx.x >> 5;
  #pragma unroll
  for (int i = 0; i < 4; i++) {
    int n = nb + tx;
    t[ty+8*i][tx] = (n < Nn) ? W[(size_t)(kb+ty+8*i)*Nn + n] : 0.f;
  }
  __syncthreads();
  #pragma unroll
  for (int i = 0; i < 4; i++) {
    int n = nb + ty + 8*i;
    Wt[(size_t)n*Kn + kb + tx] = __float2bfloat16(t[tx][ty+8*i]);
  }
}

// ---------------------------------------------------------------------------
// MFMA bf16 GEMM: C(M,N) = A(M,K) @ Bt(N,K)^T.  BM x 128 tile, BK=32,
// 4 waves in 2x2, each wave (BM/2)x64.  CMODE: 0 = fp32 linear,
// 1 = bf16 linear, 2 = bf16 head-split (dst = m*1536 + (n>>6)*128 + (n&63),
// used to write q_c/k_c directly into the flat [b,s,h,128] buffers).
// ---------------------------------------------------------------------------
template<int CMODE, int BM>
__global__ __launch_bounds__(256)
void gemm_mfma(const bf16* __restrict__ A, const bf16* __restrict__ Bt,
               void* __restrict__ Cv, int Kn, int lda, int ldb, int ldc)
{
  constexpr int MI = BM/32;          // 16-row tiles per wave
  __shared__ bf16 As[BM*32];
  __shared__ bf16 Bs[128*32];

  const int tid  = threadIdx.x;
  const int lane = tid & 63;
  const int w    = tid >> 6;
  const int col  = lane & 15, quad = lane >> 4;
  const int wr   = w >> 1, wc = w & 1;
  const size_t m0 = (size_t)blockIdx.y * BM;
  const size_t n0 = (size_t)blockIdx.x * 128;

  const int r0 = tid >> 2, seg = tid & 3;
  const bf16* Ag0 = A  + (m0 + r0)*lda + seg*8;
  const bf16* Bg0 = Bt + (n0 + r0)*ldb + seg*8;
  const bf16* Bg1 = Bg0 + (size_t)64*ldb;

  float4v acc[MI][4];
  #pragma unroll
  for (int i=0;i<MI;i++)
    #pragma unroll
    for (int j=0;j<4;j++) acc[i][j] = (float4v){0.f,0.f,0.f,0.f};

  for (int k0 = 0; k0 < Kn; k0 += 32) {
    GLDS16(Ag0 + k0, As + tid*8);
    if constexpr (BM == 128) GLDS16(Ag0 + (size_t)64*lda + k0, As + (tid+256)*8);
    GLDS16(Bg0 + k0, Bs + tid*8);
    GLDS16(Bg1 + k0, Bs + (tid+256)*8);
    __syncthreads();

    short8 af[MI], bfr[4];
    #pragma unroll
    for (int i=0;i<MI;i++)
      af[i]  = *(const short8*)&As[(wr*(BM/2) + i*16 + col)*32 + quad*8];
    #pragma unroll
    for (int j=0;j<4;j++)
      bfr[j] = *(const short8*)&Bs[(wc*64 + j*16 + col)*32 + quad*8];

    #pragma unroll
    for (int i=0;i<MI;i++)
      #pragma unroll
      for (int j=0;j<4;j++)
        acc[i][j] = __builtin_amdgcn_mfma_f32_16x16x32_bf16(af[i], bfr[j], acc[i][j], 0,0,0);
    __syncthreads();
  }

  #pragma unroll
  for (int i=0;i<MI;i++) {
    const size_t row0 = m0 + wr*(BM/2) + i*16 + quad*4;
    #pragma unroll
    for (int j=0;j<4;j++) {
      const size_t c = n0 + wc*64 + j*16 + col;
      size_t coff, ld;
      if (CMODE == 2) { coff = (c>>6)*(size_t)HD_ + (c&63); ld = HID_; }
      else            { coff = c;                            ld = (size_t)ldc; }
      #pragma unroll
      for (int r=0;r<4;r++) {
        const size_t off = (row0+r)*ld + coff;
        if (CMODE == 0) ((float*)Cv)[off] = acc[i][j][r];
        else            ((bf16*)Cv)[off]  = __float2bfloat16(acc[i][j][r]);
      }
    }
  }
}

// ---------------------------------------------------------------------------
// Fused rope + pack: reads k_r/q_r fp32 (M,768) pre-rope, writes roped bf16
// into the flat Kf/Qf [m][h][128] buffers at dims 64..127.
// ---------------------------------------------------------------------------
__global__ __launch_bounds__(256)
void rope_pack(const float* __restrict__ krr, const float* __restrict__ qrr,
               const float* __restrict__ emb,
               bf16* __restrict__ Kf, bf16* __restrict__ Qf)
{
  int idx = blockIdx.x*256 + threadIdx.x;
  int i = idx & 31;
  int hm = idx >> 5;
  int h = hm % H_, m = hm / H_;
  int s = m & (S_-1);
  float sn = emb[(size_t)s*ROT_ + i];
  float cs = emb[(size_t)s*ROT_ + 32 + i];

  const float* kr = krr + (size_t)m*(H_*ROT_) + h*ROT_;
  float x1 = kr[i], x2 = kr[32+i];
  bf16* kd = Kf + ((size_t)m*H_ + h)*HD_ + 64;
  kd[i]    = __float2bfloat16(x1*cs - x2*sn);
  kd[32+i] = __float2bfloat16(x1*sn + x2*cs);

  const float* qr = qrr + (size_t)m*(H_*ROT_) + h*ROT_;
  x1 = qr[i]; x2 = qr[32+i];
  bf16* qd = Qf + ((size_t)m*H_ + h)*HD_ + 64;
  qd[i]    = __float2bfloat16(x1*cs - x2*sn);
  qd[32+i] = __float2bfloat16(x1*sn + x2*cs);
}

// ---------------------------------------------------------------------------
// V transpose: vfl (M,1536) bf16 -> Vtg[b][h][d][s] bf16.  32x32 LDS tiles.
// grid = (HID/32, M/32).
// ---------------------------------------------------------------------------
__global__ __launch_bounds__(256)
void transV_k(const bf16* __restrict__ vfl, bf16* __restrict__ Vtg)
{
  __shared__ unsigned short t[32][36];
  const int nb = blockIdx.x*32, mb = blockIdx.y*32;
  const int c8 = threadIdx.x & 7, r = threadIdx.x >> 3;
  {
    short4v ld = *(const short4v*)((const unsigned short*)vfl +
                                   (size_t)(mb+r)*HID_ + nb + c8*4);
    #pragma unroll
    for (int k=0;k<4;k++) t[r][c8*4+k] = (unsigned short)ld[k];
  }
  __syncthreads();
  const int b = mb >> 11, s0 = mb & (S_-1);
  const int n = nb + r, hh = n >> 7, d = n & 127;
  short4v st;
  #pragma unroll
  for (int k=0;k<4;k++) st[k] = (short)t[c8*4+k][r];
  *(short4v*)((unsigned short*)Vtg +
              ((size_t)(b*H_+hh)*HD_ + d)*S_ + s0 + c8*4) = st;
}

// ---------------------------------------------------------------------------
// MFMA flash attention, causal. Block = 4 waves = 64 queries; 64-key blocks.
// All inputs pre-packed bf16: Qf/Kf flat [b,s,h,128], Vtg transposed
// [b,h,d,s].  Staging is pure vector copy (short8 load + ds_write_b128).
// Layouts (verified): A [m=lane&15][k=quad*8+j]; B [k][n=lane&15];
// C/D col=lane&15, row=quad*4+r.
// ---------------------------------------------------------------------------
#define KSTR 136   // 128+8  (272B rows, 16B aligned)
#define VSTR 72    // 64+8   (144B rows, 16B aligned)
#define PSTR 72

__global__ __launch_bounds__(256)
void attn_mfma(const bf16* __restrict__ Qf, const bf16* __restrict__ Kf,
               const bf16* __restrict__ Vtg, bf16* __restrict__ at)
{
  const int qt = (S_/64 - 1) - (int)(blockIdx.x / (B_*H_));   // long-first
  const int bh = blockIdx.x % (B_*H_);
  const int h  = bh % H_, b = bh / H_;
  const int tid  = threadIdx.x;
  const int w    = tid >> 6;
  const int lane = tid & 63;
  const int col  = lane & 15;
  const int quad = lane >> 4;

  __shared__ unsigned short Ks[64*KSTR];       // 17408 B
  __shared__ unsigned short Vt[128*VSTR];      // 18432 B
  __shared__ unsigned short Ps[4][16*PSTR];    //  9216 B

  const int q0  = qt * 64;
  const int q0w = q0 + w*16;

  const unsigned short* Kb = (const unsigned short*)Kf +
      ((size_t)b*S_*H_ + h)*HD_;
  const unsigned short* Vb = (const unsigned short*)Vtg +
      (size_t)(b*H_ + h)*HD_*S_;

  // Q fragments: dims kk*32 + quad*8 + j, direct bf16 vector loads
  short8 qf[4];
  {
    const unsigned short* qrow = (const unsigned short*)Qf +
        ((size_t)((size_t)b*S_ + q0w + col)*H_ + h)*HD_;
    #pragma unroll
    for (int kk = 0; kk < 4; kk++)
      qf[kk] = *(const short8*)(qrow + kk*32 + quad*8);
  }

  float4v O[8];
  #pragma unroll
  for (int t=0;t<8;t++) O[t] = (float4v){0.f,0.f,0.f,0.f};
  float mrow[4], lrow[4];
  #pragma unroll
  for (int r=0;r<4;r++){ mrow[r] = -1e30f; lrow[r] = 0.f; }

  const float scale = 0.08838834764831845f;   // 1/sqrt(128)
  const int nkb = qt + 1;                     // 64-key blocks

  for (int kb = 0; kb < nkb; kb++) {
    const int k0 = kb * 64;

    // stage K: 64 keys x 128 dims = 1024 16B chunks
    #pragma unroll
    for (int it = 0; it < 4; it++) {
      int c = tid + it*256;
      int key = c >> 4, doff = (c & 15)*8;
      *(short8*)&Ks[key*KSTR + doff] =
          *(const short8*)(Kb + (size_t)(k0+key)*HID_ + doff);
    }
    // stage V: 128 dims x 64 keys = 1024 16B chunks (already transposed)
    #pragma unroll
    for (int it = 0; it < 4; it++) {
      int c = tid + it*256;
      int d = c >> 3, kg = (c & 7)*8;
      *(short8*)&Vt[d*VSTR + kg] =
          *(const short8*)(Vb + (size_t)d*S_ + k0 + kg);
    }
    __syncthreads();

    // ---- S = Q K^T : up to four 16x16 key tiles ----
    float4v Sf[4];
    #pragma unroll
    for (int tc=0;tc<4;tc++) Sf[tc] = (float4v){0.f,0.f,0.f,0.f};
    #pragma unroll
    for (int tc = 0; tc < 4; tc++) {
      if (k0 + 16*tc > q0w + 15) break;        // wave-uniform tile skip
      #pragma unroll
      for (int kk = 0; kk < 4; kk++) {
        short8 bfrag = *(const short8*)&Ks[(16*tc+col)*KSTR + 32*kk + quad*8];
        Sf[tc] = __builtin_amdgcn_mfma_f32_16x16x32_bf16(qf[kk], bfrag, Sf[tc], 0,0,0);
      }
    }

    // ---- online softmax (4 rows/lane: row = quad*4 + r) ----
    float al[4];
    #pragma unroll
    for (int r = 0; r < 4; r++) {
      const int qpos = q0w + quad*4 + r;
      float sv[4]; float mt = -1e30f;
      #pragma unroll
      for (int tc = 0; tc < 4; tc++) {
        float s = Sf[tc][r] * scale;
        if (k0 + 16*tc + col > qpos) s = -1e30f;
        sv[tc] = s; mt = fmaxf(mt, s);
      }
      #pragma unroll
      for (int off = 8; off >= 1; off >>= 1)
        mt = fmaxf(mt, __shfl_xor(mt, off));
      float mnew = fmaxf(mrow[r], mt);
      float lt = 0.f;
      #pragma unroll
      for (int tc = 0; tc < 4; tc++) {
        sv[tc] = __expf(sv[tc] - mnew); lt += sv[tc];
      }
      #pragma unroll
      for (int off = 8; off >= 1; off >>= 1)
        lt += __shfl_xor(lt, off);
      al[r] = __expf(mrow[r] - mnew);
      lrow[r] = lrow[r]*al[r] + lt;
      mrow[r] = mnew;
      const int prow = quad*4 + r;
      #pragma unroll
      for (int tc = 0; tc < 4; tc++)
        Ps[w][prow*PSTR + 16*tc + col] = f2bf(sv[tc]);
    }
    #pragma unroll
    for (int t = 0; t < 8; t++)
      #pragma unroll
      for (int r = 0; r < 4; r++) O[t][r] *= al[r];

    // ---- PV: P(16x64) @ V(64x128), two K=32 steps ----
    #pragma unroll
    for (int ks = 0; ks < 2; ks++) {
      if (k0 + 32*ks > q0w + 15) break;        // wave-uniform half skip
      short8 pf = *(const short8*)&Ps[w][col*PSTR + 32*ks + quad*8];
      #pragma unroll
      for (int t = 0; t < 8; t++) {
        short8 vf = *(const short8*)&Vt[(16*t + col)*VSTR + 32*ks + quad*8];
        O[t] = __builtin_amdgcn_mfma_f32_16x16x32_bf16(pf, vf, O[t], 0,0,0);
      }
    }
    __syncthreads();
  }

  // epilogue: divide by l, store bf16 to flat at[(b,s,h*128)]
  #pragma unroll
  for (int r = 0; r < 4; r++) {
    const float linv = 1.f / lrow[r];
    const size_t mq = (size_t)b*S_ + q0w + quad*4 + r;
    bf16* dst = at + mq*HID_ + h*HD_ + col;
    #pragma unroll
    for (int t = 0; t < 8; t++)
      dst[16*t] = __float2bfloat16(O[t][r] * linv);
  }
}

extern "C" void kernel_launch(void* const* d_in, const int* in_sizes, int n_in,
                              void* d_out, int out_size, void* d_ws, size_t ws_size,
                              hipStream_t stream)
{
  float* out = (float*)d_out;

  // Size guard tripwire.
  static const int sz_dict[10] = {6291456,131072,294912,294912,147456,
                                  147456,294912,1179648,147456,2359296};
  int bad = -1;
  if (n_in < 10) bad = 15;
  else {
    for (int i = 0; i < 10; i++)
      if (in_sizes[i] != sz_dict[i]) { bad = i; break; }
  }
  if (bad >= 0) {
    float v = 1.0e6f * (float)(1 + bad);
    if (bad < 10) v += (float)(in_sizes[bad] % 1000000);
    fillf_k<<<(out_size + 255)/256, 256, 0, stream>>>(out, v, out_size);
    return;
  }

  const float* hidden = (const float*)d_in[0];
  const float* emb    = (const float*)d_in[1];
  const float* Wkvd   = (const float*)d_in[2];
  const float* Wqd    = (const float*)d_in[3];
  const float* Wku    = (const float*)d_in[4];
  const float* Wqu    = (const float*)d_in[5];
  const float* Wvu    = (const float*)d_in[6];
  const float* Wrk    = (const float*)d_in[7];
  const float* Wrq    = (const float*)d_in[8];
  const float* Wo     = (const float*)d_in[9];

  // --- workspace carve (256B aligned each) ---
  char* wp = (char*)d_ws;
  size_t used = 0;
  auto alloc = [&](size_t bytes) -> void* {
    void* p = wp + used;
    used += (bytes + 255) & ~(size_t)255;
    return p;
  };
  bf16*  hb   = (bf16*)alloc((size_t)M_*HID_*2);        // hidden bf16
  bf16*  dout = (bf16*)alloc((size_t)M_*512*2);         // fused kvd|qd (M,512)
  float* krr  = (float*)alloc((size_t)M_*(H_*ROT_)*4);  // (M,768) fp32 pre-rope
  float* qrr  = (float*)alloc((size_t)M_*(H_*ROT_)*4);
  bf16*  Kf   = (bf16*)alloc((size_t)M_*HID_*2);        // [m][h][128] bf16
  bf16*  Qf   = (bf16*)alloc((size_t)M_*HID_*2);
  bf16*  vfl  = (bf16*)alloc((size_t)M_*HID_*2);        // (M,1536) bf16
  bf16*  Vtg  = (bf16*)alloc((size_t)B_*H_*HD_*S_*2);   // [b][h][d][s] bf16
  bf16*  at   = (bf16*)alloc((size_t)M_*HID_*2);
  bf16*  WdT  = (bf16*)alloc((size_t)512*HID_*2);       // fused (512,1536)
  bf16*  WkuT = (bf16*)alloc((size_t)(H_*ROT_)*LAT_*2);
  bf16*  WquT = (bf16*)alloc((size_t)(H_*ROT_)*LAT_*2);
  bf16*  WvuT = (bf16*)alloc((size_t)HID_*LAT_*2);
  bf16*  WrkT = (bf16*)alloc((size_t)(H_*ROT_)*HID_*2);
  bf16*  WrqT = (bf16*)alloc((size_t)(H_*ROT_)*LAT_*2);
  bf16*  WoT  = (bf16*)alloc((size_t)HID_*HID_*2);

  if (used > ws_size) {   // workspace tripwire
    fillf_k<<<(out_size + 255)/256, 256, 0, stream>>>(out, 5.0e7f, out_size);
    return;
  }

  // --- packs (depend only on inputs) ---
  packA_k<<<(M_*HID_)/1024, 256, 0, stream>>>(hidden, hb);
  packT_k<<<dim3(HID_/32, LATP_/32),    256, 0, stream>>>(Wkvd, WdT,                    HID_, LAT_);
  packT_k<<<dim3(HID_/32, LATP_/32),    256, 0, stream>>>(Wqd,  WdT + (size_t)256*HID_, HID_, LAT_);
  packT_k<<<dim3(LAT_/32, (H_*ROT_)/32),256, 0, stream>>>(Wku,  WkuT, LAT_, H_*ROT_);
  packT_k<<<dim3(LAT_/32, (H_*ROT_)/32),256, 0, stream>>>(Wqu,  WquT, LAT_, H_*ROT_);
  packT_k<<<dim3(LAT_/32, HID_/32),     256, 0, stream>>>(Wvu,  WvuT, LAT_, HID_);
  packT_k<<<dim3(HID_/32, (H_*ROT_)/32),256, 0, stream>>>(Wrk,  WrkT, HID_, H_*ROT_);
  packT_k<<<dim3(LAT_/32, (H_*ROT_)/32),256, 0, stream>>>(Wrq,  WrqT, LAT_, H_*ROT_);
  packT_k<<<dim3(HID_/32, HID_/32),     256, 0, stream>>>(Wo,   WoT,  HID_, HID_);

  // --- MFMA projection GEMMs ---
  // fused down-proj: (M,512) = hb @ WdT^T   (cols 0..255 kvd, 256..511 qd)
  gemm_mfma<1,64><<<dim3(512/128, M_/64), 256, 0, stream>>>(hb, WdT, dout, HID_, HID_, HID_, 512);
  // k_c / q_c written straight into Kf/Qf (head-split bf16 epilogue)
  gemm_mfma<2,64><<<dim3((H_*ROT_)/128, M_/64), 256, 0, stream>>>(dout,     WkuT, Kf, LAT_, 512, LAT_, 0);
  gemm_mfma<2,64><<<dim3((H_*ROT_)/128, M_/64), 256, 0, stream>>>(dout+256, WquT, Qf, LAT_, 512, LAT_, 0);
  gemm_mfma<1,128><<<dim3(HID_/128, M_/128), 256, 0, stream>>>(dout, WvuT, vfl, LAT_, 512, LAT_, HID_);
  gemm_mfma<0,64><<<dim3((H_*ROT_)/128, M_/64), 256, 0, stream>>>(hb,       WrkT, krr, HID_, HID_, HID_, H_*ROT_);
  gemm_mfma<0,64><<<dim3((H_*ROT_)/128, M_/64), 256, 0, stream>>>(dout+256, WrqT, qrr, LAT_, 512, LAT_, H_*ROT_);

  // rope halves of Kf/Qf + V transpose
  rope_pack<<<(M_*H_*32)/256, 256, 0, stream>>>(krr, qrr, emb, Kf, Qf);
  transV_k<<<dim3(HID_/32, M_/32), 256, 0, stream>>>(vfl, Vtg);

  // MFMA flash attention (64-query blocks, 64-key tiles)
  attn_mfma<<<B_*H_*(S_/64), 256, 0, stream>>>(Qf, Kf, Vtg, at);

  gemm_mfma<0,128><<<dim3(HID_/128, M_/128), 256, 0, stream>>>(at, WoT, out, HID_, HID_, HID_, HID_);
}

// Round 3
// 285.222 us; speedup vs baseline: 4.2523x; 1.2244x over previous
//
#include <hip/hip_runtime.h>
#include <hip/hip_bf16.h>

#define B_ 2
#define S_ 2048
#define HID_ 1536
#define H_ 12
#define HD_ 128
#define LAT_ 192
#define ROT_ 64
#define M_ (B_*S_)         // 4096

typedef __hip_bfloat16 bf16;

using short8  = __attribute__((ext_vector_type(8))) short;
using short4v = __attribute__((ext_vector_type(4))) short;
using float4v = __attribute__((ext_vector_type(4))) float;

__device__ __forceinline__ unsigned short f2bf(float f) {
  __hip_bfloat16 h = __float2bfloat16(f);
  unsigned short u; __builtin_memcpy(&u, &h, 2); return u;
}

// async global->LDS, 16B per lane (wave-uniform LDS base + lane*16)
#define GLDS16(gp, lp) __builtin_amdgcn_global_load_lds( \
    (__attribute__((address_space(1))) void*)(size_t)(gp), \
    (__attribute__((address_space(3))) void*)(lp), 16, 0, 0)

__global__ __launch_bounds__(256)
void fillf_k(float* __restrict__ out, float v, int n)
{
  int i = blockIdx.x*256 + threadIdx.x;
  if (i < n) out[i] = v;
}

// ---------------------------------------------------------------------------
// fp32 -> bf16 elementwise pack (n multiple of 1024)
// ---------------------------------------------------------------------------
__global__ __launch_bounds__(256)
void packA_k(const float* __restrict__ in, bf16* __restrict__ out)
{
  int i = (blockIdx.x*256 + threadIdx.x)*4;
  float4 v = *(const float4*)&in[i];
  short4v o;
  o[0] = (short)f2bf(v.x); o[1] = (short)f2bf(v.y);
  o[2] = (short)f2bf(v.z); o[3] = (short)f2bf(v.w);
  *(short4v*)&out[i] = o;
}

// ---------------------------------------------------------------------------
// Weight transpose+pack: W(K,N) fp32 -> Wt(N,K) bf16.
// grid = (Kn/32, Nn/32), 256 threads, LDS 32x33 tile.
// ---------------------------------------------------------------------------
__global__ __launch_bounds__(256)
void packT_k(const float* __restrict__ W, bf16* __restrict__ Wt,
             int Kn, int Nn)
{
  __shared__ float t[32][33];
  const int kb = blockIdx.x*32, nb = blockIdx.y*32;
  const int tx = threadIdx.x & 31, ty = threadIdx.x >> 5;
  #pragma unroll
  for (int i = 0; i < 4; i++)
    t[ty+8*i][tx] = W[(size_t)(kb+ty+8*i)*Nn + nb + tx];
  __syncthreads();
  #pragma unroll
  for (int i = 0; i < 4; i++)
    Wt[(size_t)(nb + ty + 8*i)*Kn + kb + tx] = __float2bfloat16(t[tx][ty+8*i]);
}

// Batched-3 variant: blockIdx.z selects (src,dst,Nn); early-exit on nb>=Nn.
__global__ __launch_bounds__(256)
void packT3_k(const float* __restrict__ s0, const float* __restrict__ s1,
              const float* __restrict__ s2, bf16* __restrict__ d0,
              bf16* __restrict__ d1, bf16* __restrict__ d2,
              int Kn, int N0, int N1, int N2)
{
  const float* W; bf16* Wt; int Nn;
  if (blockIdx.z == 0)      { W = s0; Wt = d0; Nn = N0; }
  else if (blockIdx.z == 1) { W = s1; Wt = d1; Nn = N1; }
  else                      { W = s2; Wt = d2; Nn = N2; }
  const int kb = blockIdx.x*32, nb = blockIdx.y*32;
  if (nb >= Nn) return;
  __shared__ float t[32][33];
  const int tx = threadIdx.x & 31, ty = threadIdx.x >> 5;
  #pragma unroll
  for (int i = 0; i < 4; i++)
    t[ty+8*i][tx] = W[(size_t)(kb+ty+8*i)*Nn + nb + tx];
  __syncthreads();
  #pragma unroll
  for (int i = 0; i < 4; i++)
    Wt[(size_t)(nb + ty + 8*i)*Kn + kb + tx] = __float2bfloat16(t[tx][ty+8*i]);
}

// ---------------------------------------------------------------------------
// MFMA bf16 GEMM: C(M,N) = A(M,K) @ Bt(N,K)^T.  BM x 128 tile, BK=64,
// 4 waves in 2x2, each wave (BM/2)x64.  LDS staged linearly via
// global_load_lds with XOR-swizzled GLOBAL source (seg ^= row&7) so the
// swizzled ds_read_b128 is ~conflict-free (T2 both-sides rule, m173/m201).
// CMODE epilogues (split points on 128-tile boundaries, wave-uniform):
//   0: fp32 linear (ldc)            [W_o output]
//   3: c<768 -> Kf head-split bf16; else vfl bf16 linear (ldc 1536)
//   4: c<768 -> Qf head-split bf16; else qrr fp32 linear (ldc 768)
//   5: c<384 -> dout bf16 (ldc 384); else krr fp32 linear (ldc 768)
// ---------------------------------------------------------------------------
template<int CMODE, int BM>
__global__ __launch_bounds__(256)
void gemm_mfma(const bf16* __restrict__ A, const bf16* __restrict__ Bt,
               void* __restrict__ Cv, void* __restrict__ Cv2,
               int Kn, int lda, int ldb, int ldc)
{
  constexpr int MI  = BM/32;         // 16-row tiles per wave
  constexpr int ITA = BM/32;         // A staging calls (BM*8/256)
  __shared__ bf16 As[(size_t)BM*64];
  __shared__ bf16 Bs[128*64];

  const int tid  = threadIdx.x;
  const int lane = tid & 63;
  const int w    = tid >> 6;
  const int col  = lane & 15, quad = lane >> 4;
  const int wr   = w >> 1, wc = w & 1;
  const size_t m0 = (size_t)blockIdx.y * BM;
  const size_t n0 = (size_t)blockIdx.x * 128;

  const bf16* ag[ITA]; const bf16* bg[4];
  #pragma unroll
  for (int it = 0; it < ITA; it++) {
    int c = tid + it*256, row = c >> 3, seg = c & 7;
    ag[it] = A + (m0 + row)*lda + (size_t)((seg ^ (row & 7))*8);
  }
  #pragma unroll
  for (int it = 0; it < 4; it++) {
    int c = tid + it*256, row = c >> 3, seg = c & 7;
    bg[it] = Bt + (n0 + row)*ldb + (size_t)((seg ^ (row & 7))*8);
  }

  float4v acc[MI][4];
  #pragma unroll
  for (int i=0;i<MI;i++)
    #pragma unroll
    for (int j=0;j<4;j++) acc[i][j] = (float4v){0.f,0.f,0.f,0.f};

  for (int k0 = 0; k0 < Kn; k0 += 64) {
    #pragma unroll
    for (int it = 0; it < ITA; it++)
      GLDS16(ag[it] + k0, As + (size_t)(tid + it*256)*8);
    #pragma unroll
    for (int it = 0; it < 4; it++)
      GLDS16(bg[it] + k0, Bs + (size_t)(tid + it*256)*8);
    __syncthreads();

    short8 af[MI][2], bfr[4][2];
    #pragma unroll
    for (int i=0;i<MI;i++) {
      const int ar = wr*(BM/2) + i*16 + col;
      #pragma unroll
      for (int k2=0;k2<2;k2++)
        af[i][k2] = *(const short8*)&As[ar*64 + ((k2*4+quad)^(ar&7))*8];
    }
    #pragma unroll
    for (int j=0;j<4;j++) {
      const int br = wc*64 + j*16 + col;
      #pragma unroll
      for (int k2=0;k2<2;k2++)
        bfr[j][k2] = *(const short8*)&Bs[br*64 + ((k2*4+quad)^(br&7))*8];
    }

    #pragma unroll
    for (int k2=0;k2<2;k2++)
      #pragma unroll
      for (int i=0;i<MI;i++)
        #pragma unroll
        for (int j=0;j<4;j++)
          acc[i][j] = __builtin_amdgcn_mfma_f32_16x16x32_bf16(af[i][k2], bfr[j][k2], acc[i][j], 0,0,0);
    __syncthreads();
  }

  #pragma unroll
  for (int i=0;i<MI;i++) {
    const size_t row0 = m0 + wr*(BM/2) + i*16 + quad*4;
    #pragma unroll
    for (int j=0;j<4;j++) {
      const int c = (int)n0 + wc*64 + j*16 + col;
      #pragma unroll
      for (int r=0;r<4;r++) {
        const size_t row = row0 + r;
        const float v = acc[i][j][r];
        if constexpr (CMODE == 0) {
          ((float*)Cv)[row*ldc + c] = v;
        } else if constexpr (CMODE == 3) {
          if (n0 < 768) ((bf16*)Cv)[row*HID_ + (c>>6)*HD_ + (c&63)] = __float2bfloat16(v);
          else          ((bf16*)Cv2)[row*HID_ + (c-768)] = __float2bfloat16(v);
        } else if constexpr (CMODE == 4) {
          if (n0 < 768) ((bf16*)Cv)[row*HID_ + (c>>6)*HD_ + (c&63)] = __float2bfloat16(v);
          else          ((float*)Cv2)[row*768 + (c-768)] = v;
        } else {       // 5
          if (n0 < 384) ((bf16*)Cv)[row*384 + c] = __float2bfloat16(v);
          else          ((float*)Cv2)[row*768 + (c-384)] = v;
        }
      }
    }
  }
}

// ---------------------------------------------------------------------------
// Fused rope + pack: reads k_r/q_r fp32 (M,768) pre-rope, writes roped bf16
// into the flat Kf/Qf [m][h][128] buffers at dims 64..127.
// ---------------------------------------------------------------------------
__global__ __launch_bounds__(256)
void rope_pack(const float* __restrict__ krr, const float* __restrict__ qrr,
               const float* __restrict__ emb,
               bf16* __restrict__ Kf, bf16* __restrict__ Qf)
{
  int idx = blockIdx.x*256 + threadIdx.x;
  int i = idx & 31;
  int hm = idx >> 5;
  int h = hm % H_, m = hm / H_;
  int s = m & (S_-1);
  float sn = emb[(size_t)s*ROT_ + i];
  float cs = emb[(size_t)s*ROT_ + 32 + i];

  const float* kr = krr + (size_t)m*(H_*ROT_) + h*ROT_;
  float x1 = kr[i], x2 = kr[32+i];
  bf16* kd = Kf + ((size_t)m*H_ + h)*HD_ + 64;
  kd[i]    = __float2bfloat16(x1*cs - x2*sn);
  kd[32+i] = __float2bfloat16(x1*sn + x2*cs);

  const float* qr = qrr + (size_t)m*(H_*ROT_) + h*ROT_;
  x1 = qr[i]; x2 = qr[32+i];
  bf16* qd = Qf + ((size_t)m*H_ + h)*HD_ + 64;
  qd[i]    = __float2bfloat16(x1*cs - x2*sn);
  qd[32+i] = __float2bfloat16(x1*sn + x2*cs);
}

// ---------------------------------------------------------------------------
// V transpose: vfl (M,1536) bf16 -> Vtg[b][h][d][s] bf16.  32x32 LDS tiles.
// ---------------------------------------------------------------------------
__global__ __launch_bounds__(256)
void transV_k(const bf16* __restrict__ vfl, bf16* __restrict__ Vtg)
{
  __shared__ unsigned short t[32][36];
  const int nb = blockIdx.x*32, mb = blockIdx.y*32;
  const int c8 = threadIdx.x & 7, r = threadIdx.x >> 3;
  {
    short4v ld = *(const short4v*)((const unsigned short*)vfl +
                                   (size_t)(mb+r)*HID_ + nb + c8*4);
    #pragma unroll
    for (int k=0;k<4;k++) t[r][c8*4+k] = (unsigned short)ld[k];
  }
  __syncthreads();
  const int b = mb >> 11, s0 = mb & (S_-1);
  const int n = nb + r, hh = n >> 7, d = n & 127;
  short4v st;
  #pragma unroll
  for (int k=0;k<4;k++) st[k] = (short)t[c8*4+k][r];
  *(short4v*)((unsigned short*)Vtg +
              ((size_t)(b*H_+hh)*HD_ + d)*S_ + s0 + c8*4) = st;
}

// ---------------------------------------------------------------------------
// MFMA flash attention, causal. Block = 4 waves = 64 queries; 64-key blocks.
// SWAPPED QK^T: Sf = mfma(K, Q) -> D[key][q]: lane owns ONE q (=q0w+col)
// with 16 key-values in registers -> softmax reduce = reg ops + 2 shfl_xor
// (vs 32 shfl in the row-spread layout).  T14 async-stage: next tile's K/V
// loaded into regs during compute, ds_written after the consume barrier.
// PV unchanged: O rows = quad*4+r, so al/l are broadcast per row (4 shfl).
// ---------------------------------------------------------------------------
#define KSTR 136   // 128+8  (272B rows, 16B aligned)
#define VSTR 72    // 64+8   (144B rows, 16B aligned)
#define PSTR 72

__global__ __launch_bounds__(256)
void attn_mfma(const bf16* __restrict__ Qf, const bf16* __restrict__ Kf,
               const bf16* __restrict__ Vtg, bf16* __restrict__ at)
{
  const int qt = (S_/64 - 1) - (int)(blockIdx.x / (B_*H_));   // long-first
  const int bh = blockIdx.x % (B_*H_);
  const int h  = bh % H_, b = bh / H_;
  const int tid  = threadIdx.x;
  const int w    = tid >> 6;
  const int lane = tid & 63;
  const int col  = lane & 15;
  const int quad = lane >> 4;

  __shared__ unsigned short Ks[64*KSTR];       // 17408 B
  __shared__ unsigned short Vt[128*VSTR];      // 18432 B
  __shared__ unsigned short Ps[4][16*PSTR];    //  9216 B

  const int q0  = qt * 64;
  const int q0w = q0 + w*16;

  const unsigned short* Kb = (const unsigned short*)Kf +
      ((size_t)b*S_*H_ + h)*HD_;
  const unsigned short* Vb = (const unsigned short*)Vtg +
      (size_t)(b*H_ + h)*HD_*S_;

  // staging address precompute (constant per thread)
  const unsigned short* kgp[4]; unsigned short* kdst[4];
  const unsigned short* vgp[4]; unsigned short* vdst[4];
  #pragma unroll
  for (int it = 0; it < 4; it++) {
    int c = tid + it*256;
    int key = c >> 4, doff = (c & 15)*8;
    kgp[it]  = Kb + (size_t)key*HID_ + doff;
    kdst[it] = &Ks[key*KSTR + doff];
    int d = c >> 3, kg = (c & 7)*8;
    vgp[it]  = Vb + (size_t)d*S_ + kg;
    vdst[it] = &Vt[d*VSTR + kg];
  }

  // Q fragments (serve as the B-operand of the swapped QK^T unchanged)
  short8 qf[4];
  {
    const unsigned short* qrow = (const unsigned short*)Qf +
        ((size_t)((size_t)b*S_ + q0w + col)*H_ + h)*HD_;
    #pragma unroll
    for (int kk = 0; kk < 4; kk++)
      qf[kk] = *(const short8*)(qrow + kk*32 + quad*8);
  }

  float4v O[8];
  #pragma unroll
  for (int t=0;t<8;t++) O[t] = (float4v){0.f,0.f,0.f,0.f};
  float m_ln = -1e30f, l_ln = 0.f;

  const float scale = 0.08838834764831845f;   // 1/sqrt(128)
  const int nkb = qt + 1;                     // 64-key blocks

  // prologue: load tile 0 into regs
  short8 kr[4], vr[4];
  #pragma unroll
  for (int it = 0; it < 4; it++) {
    kr[it] = *(const short8*)kgp[it];
    vr[it] = *(const short8*)vgp[it];
  }

  for (int kb = 0; kb < nkb; kb++) {
    const int k0 = kb * 64;

    // commit staged regs to LDS
    #pragma unroll
    for (int it = 0; it < 4; it++) *(short8*)kdst[it] = kr[it];
    #pragma unroll
    for (int it = 0; it < 4; it++) *(short8*)vdst[it] = vr[it];
    __syncthreads();

    // T14: issue next tile's loads; latency hides under compute
    if (kb + 1 < nkb) {
      const size_t kn = (size_t)(k0 + 64);
      #pragma unroll
      for (int it = 0; it < 4; it++) {
        kr[it] = *(const short8*)(kgp[it] + kn*HID_);
        vr[it] = *(const short8*)(vgp[it] + kn);
      }
    }

    // ---- swapped QK^T: D[key][q], lane q = q0w+col ----
    float4v Sf[4];
    #pragma unroll
    for (int tc=0;tc<4;tc++) Sf[tc] = (float4v){0.f,0.f,0.f,0.f};
    __builtin_amdgcn_s_setprio(1);
    #pragma unroll
    for (int tc = 0; tc < 4; tc++) {
      if (k0 + 16*tc <= q0w + 15) {            // wave-uniform tile skip
        #pragma unroll
        for (int kk = 0; kk < 4; kk++) {
          short8 kfrag = *(const short8*)&Ks[(16*tc+col)*KSTR + 32*kk + quad*8];
          Sf[tc] = __builtin_amdgcn_mfma_f32_16x16x32_bf16(kfrag, qf[kk], Sf[tc], 0,0,0);
        }
      }
    }
    __builtin_amdgcn_s_setprio(0);

    // ---- softmax: lane-local over 16 key-values (k = tc*16+quad*4+r) ----
    const int qrel = q0w + col - k0;
    float sv[4][4];
    float mt = -1e30f;
    #pragma unroll
    for (int tc = 0; tc < 4; tc++)
      #pragma unroll
      for (int r = 0; r < 4; r++) {
        float s = Sf[tc][r] * scale;
        if (tc*16 + quad*4 + r > qrel) s = -1e30f;
        sv[tc][r] = s;
        mt = fmaxf(mt, s);
      }
    mt = fmaxf(mt, __shfl_xor(mt, 16));
    mt = fmaxf(mt, __shfl_xor(mt, 32));
    const float mnew = fmaxf(m_ln, mt);
    float lt = 0.f;
    #pragma unroll
    for (int tc = 0; tc < 4; tc++)
      #pragma unroll
      for (int r = 0; r < 4; r++) {
        sv[tc][r] = __expf(sv[tc][r] - mnew);
        lt += sv[tc][r];
      }
    lt += __shfl_xor(lt, 16);
    lt += __shfl_xor(lt, 32);
    const float al = __expf(m_ln - mnew);
    l_ln = l_ln * al + lt;
    m_ln = mnew;

    // write P row q=col: 4 bf16 per tc, one ds_write_b64 each
    #pragma unroll
    for (int tc = 0; tc < 4; tc++) {
      short4v pw;
      pw[0] = (short)f2bf(sv[tc][0]); pw[1] = (short)f2bf(sv[tc][1]);
      pw[2] = (short)f2bf(sv[tc][2]); pw[3] = (short)f2bf(sv[tc][3]);
      *(short4v*)&Ps[w][col*PSTR + tc*16 + quad*4] = pw;
    }

    // O rescale: O rows are q = quad*4+r -> fetch their al (identical in
    // all 4 quads' col=quad*4+r lanes; take the quad-0 lane)
    float alr[4];
    #pragma unroll
    for (int r = 0; r < 4; r++) alr[r] = __shfl(al, quad*4 + r);
    #pragma unroll
    for (int t = 0; t < 8; t++)
      #pragma unroll
      for (int r = 0; r < 4; r++) O[t][r] *= alr[r];

    // ---- PV: P(16x64) @ V(64x128), two K=32 steps ----
    __builtin_amdgcn_s_setprio(1);
    #pragma unroll
    for (int ks = 0; ks < 2; ks++) {
      if (k0 + 32*ks <= q0w + 15) {            // wave-uniform half skip
        short8 pf = *(const short8*)&Ps[w][col*PSTR + 32*ks + quad*8];
        #pragma unroll
        for (int t = 0; t < 8; t++) {
          short8 vf = *(const short8*)&Vt[(16*t + col)*VSTR + 32*ks + quad*8];
          O[t] = __builtin_amdgcn_mfma_f32_16x16x32_bf16(pf, vf, O[t], 0,0,0);
        }
      }
    }
    __builtin_amdgcn_s_setprio(0);
    __syncthreads();
  }

  // epilogue: rows q = quad*4+r need l of those rows
  float lr[4];
  #pragma unroll
  for (int r = 0; r < 4; r++) lr[r] = __shfl(l_ln, quad*4 + r);
  #pragma unroll
  for (int r = 0; r < 4; r++) {
    const float linv = 1.f / lr[r];
    const size_t mq = (size_t)b*S_ + q0w + quad*4 + r;
    bf16* dst = at + mq*HID_ + h*HD_ + col;
    #pragma unroll
    for (int t = 0; t < 8; t++)
      dst[16*t] = __float2bfloat16(O[t][r] * linv);
  }
}

extern "C" void kernel_launch(void* const* d_in, const int* in_sizes, int n_in,
                              void* d_out, int out_size, void* d_ws, size_t ws_size,
                              hipStream_t stream)
{
  float* out = (float*)d_out;

  // Size guard tripwire.
  static const int sz_dict[10] = {6291456,131072,294912,294912,147456,
                                  147456,294912,1179648,147456,2359296};
  int bad = -1;
  if (n_in < 10) bad = 15;
  else {
    for (int i = 0; i < 10; i++)
      if (in_sizes[i] != sz_dict[i]) { bad = i; break; }
  }
  if (bad >= 0) {
    float v = 1.0e6f * (float)(1 + bad);
    if (bad < 10) v += (float)(in_sizes[bad] % 1000000);
    fillf_k<<<(out_size + 255)/256, 256, 0, stream>>>(out, v, out_size);
    return;
  }

  const float* hidden = (const float*)d_in[0];
  const float* emb    = (const float*)d_in[1];
  const float* Wkvd   = (const float*)d_in[2];
  const float* Wqd    = (const float*)d_in[3];
  const float* Wku    = (const float*)d_in[4];
  const float* Wqu    = (const float*)d_in[5];
  const float* Wvu    = (const float*)d_in[6];
  const float* Wrk    = (const float*)d_in[7];
  const float* Wrq    = (const float*)d_in[8];
  const float* Wo     = (const float*)d_in[9];

  // --- workspace carve (256B aligned each) ---
  char* wp = (char*)d_ws;
  size_t used = 0;
  auto alloc = [&](size_t bytes) -> void* {
    void* p = wp + used;
    used += (bytes + 255) & ~(size_t)255;
    return p;
  };
  bf16*  hb    = (bf16*)alloc((size_t)M_*HID_*2);        // hidden bf16
  bf16*  dout  = (bf16*)alloc((size_t)M_*384*2);         // [kvd|qd] (M,384)
  float* krr   = (float*)alloc((size_t)M_*(H_*ROT_)*4);  // (M,768) fp32
  float* qrr   = (float*)alloc((size_t)M_*(H_*ROT_)*4);
  bf16*  Kf    = (bf16*)alloc((size_t)M_*HID_*2);        // [m][h][128] bf16
  bf16*  Qf    = (bf16*)alloc((size_t)M_*HID_*2);
  bf16*  vfl   = (bf16*)alloc((size_t)M_*HID_*2);        // (M,1536) bf16
  bf16*  Vtg   = (bf16*)alloc((size_t)B_*H_*HD_*S_*2);   // [b][h][d][s] bf16
  bf16*  at    = (bf16*)alloc((size_t)M_*HID_*2);
  bf16*  WdkrT = (bf16*)alloc((size_t)1152*HID_*2);      // [WkvdT;WqdT;WrkT]
  bf16*  WkvuT = (bf16*)alloc((size_t)2304*LAT_*2);      // [WkuT;WvuT]
  bf16*  WqurT = (bf16*)alloc((size_t)1536*LAT_*2);      // [WquT;WrqT]
  bf16*  WoT   = (bf16*)alloc((size_t)HID_*HID_*2);

  if (used > ws_size) {   // workspace tripwire
    fillf_k<<<(out_size + 255)/256, 256, 0, stream>>>(out, 5.0e7f, out_size);
    return;
  }

  // --- packs ---
  packA_k<<<(M_*HID_)/1024, 256, 0, stream>>>(hidden, hb);
  packT3_k<<<dim3(48,24,3), 256, 0, stream>>>(
      Wkvd, Wqd, Wrk,
      WdkrT, WdkrT + (size_t)192*HID_, WdkrT + (size_t)384*HID_,
      HID_, LAT_, LAT_, H_*ROT_);
  packT3_k<<<dim3(6,24,3), 256, 0, stream>>>(
      Wku, Wqu, Wrq,
      WkvuT, WqurT, WqurT + (size_t)768*LAT_,
      LAT_, H_*ROT_, H_*ROT_, H_*ROT_);
  packT_k<<<dim3(6,48),  256, 0, stream>>>(Wvu, WkvuT + (size_t)768*LAT_, LAT_, HID_);
  packT_k<<<dim3(48,48), 256, 0, stream>>>(Wo,  WoT, HID_, HID_);

  // --- MFMA projection GEMMs (consolidated) ---
  // hb @ [WkvdT;WqdT;WrkT]^T -> dout(384) | krr(768)
  gemm_mfma<5,64><<<dim3(9, M_/64),  256, 0, stream>>>(hb,        WdkrT, dout, krr, HID_, HID_, HID_, 0);
  // kvd @ [WkuT;WvuT]^T -> Kf head-split | vfl
  gemm_mfma<3,64><<<dim3(18, M_/64), 256, 0, stream>>>(dout,      WkvuT, Kf,   vfl, LAT_, 384, LAT_, 0);
  // qd @ [WquT;WrqT]^T -> Qf head-split | qrr fp32
  gemm_mfma<4,64><<<dim3(12, M_/64), 256, 0, stream>>>(dout+192,  WqurT, Qf,   qrr, LAT_, 384, LAT_, 0);

  // rope halves of Kf/Qf + V transpose
  rope_pack<<<(M_*H_*32)/256, 256, 0, stream>>>(krr, qrr, emb, Kf, Qf);
  transV_k<<<dim3(HID_/32, M_/32), 256, 0, stream>>>(vfl, Vtg);

  // MFMA flash attention (64-query blocks, 64-key tiles)
  attn_mfma<<<B_*H_*(S_/64), 256, 0, stream>>>(Qf, Kf, Vtg, at);

  gemm_mfma<0,128><<<dim3(HID_/128, M_/128), 256, 0, stream>>>(at, WoT, out, nullptr, HID_, HID_, HID_, HID_);
}

// Round 4
// 266.473 us; speedup vs baseline: 4.5515x; 1.0704x over previous
//
#include <hip/hip_runtime.h>
#include <hip/hip_bf16.h>

#define B_ 2
#define S_ 2048
#define HID_ 1536
#define H_ 12
#define HD_ 128
#define LAT_ 192
#define ROT_ 64
#define M_ (B_*S_)         // 4096

typedef __hip_bfloat16 bf16;

using short8  = __attribute__((ext_vector_type(8))) short;
using short4v = __attribute__((ext_vector_type(4))) short;
using float4v = __attribute__((ext_vector_type(4))) float;

__device__ __forceinline__ unsigned short f2bf(float f) {
  __hip_bfloat16 h = __float2bfloat16(f);
  unsigned short u; __builtin_memcpy(&u, &h, 2); return u;
}

// async global->LDS, 16B per lane (wave-uniform LDS base + lane*16)
#define GLDS16(gp, lp) __builtin_amdgcn_global_load_lds( \
    (__attribute__((address_space(1))) void*)(size_t)(gp), \
    (__attribute__((address_space(3))) void*)(lp), 16, 0, 0)

__global__ __launch_bounds__(256)
void fillf_k(float* __restrict__ out, float v, int n)
{
  int i = blockIdx.x*256 + threadIdx.x;
  if (i < n) out[i] = v;
}

// ---------------------------------------------------------------------------
// Batched-4 weight transpose+pack: W(K,N) fp32 -> Wt(N,K) bf16.
// All 4 weights share Kn.  grid = (Kn/32, maxN/32, 4); early-exit on nb>=Nn.
// ---------------------------------------------------------------------------
__global__ __launch_bounds__(256)
void packT4_k(const float* __restrict__ s0, const float* __restrict__ s1,
              const float* __restrict__ s2, const float* __restrict__ s3,
              bf16* __restrict__ d0, bf16* __restrict__ d1,
              bf16* __restrict__ d2, bf16* __restrict__ d3,
              int Kn, int N0, int N1, int N2, int N3)
{
  const float* W; bf16* Wt; int Nn;
  switch (blockIdx.z) {
    case 0:  W = s0; Wt = d0; Nn = N0; break;
    case 1:  W = s1; Wt = d1; Nn = N1; break;
    case 2:  W = s2; Wt = d2; Nn = N2; break;
    default: W = s3; Wt = d3; Nn = N3; break;
  }
  const int kb = blockIdx.x*32, nb = blockIdx.y*32;
  if (nb >= Nn) return;
  __shared__ float t[32][33];
  const int tx = threadIdx.x & 31, ty = threadIdx.x >> 5;
  #pragma unroll
  for (int i = 0; i < 4; i++)
    t[ty+8*i][tx] = W[(size_t)(kb+ty+8*i)*Nn + nb + tx];
  __syncthreads();
  #pragma unroll
  for (int i = 0; i < 4; i++)
    Wt[(size_t)(nb + ty + 8*i)*Kn + kb + tx] = __float2bfloat16(t[tx][ty+8*i]);
}

// ---------------------------------------------------------------------------
// MFMA bf16 GEMM: C(M,N) = A(M,K) @ Bt(N,K)^T.  BM x 128 tile, BK=64,
// 4 waves 2x2, each wave (BM/2)x64.  B staged via global_load_lds with
// XOR-swizzled GLOBAL source (T2 both-sides rule); A likewise, or (AF32)
// reg-staged from fp32 with on-the-fly bf16 cvt + swizzled ds_write_b128.
// CMODE epilogues (block-uniform splits on 128-tile boundaries):
//   0: fp32 linear (ldc)                                [out = at @ Wo]
//   5: c<384 -> dout bf16 (ldc 384); else ROPE -> Kf dims 64..127
//   3: c<768 -> Kf head-split bf16 (k_c); else V transposed -> Vtg[b,h,d,s]
//   4: c<768 -> Qf head-split bf16 (q_c); else ROPE -> Qf dims 64..127
// Rope pairing is lane-local: acc[i][j] (d=j*16+col<32) pairs acc[i][j+2].
// ---------------------------------------------------------------------------
template<int CMODE, int BM, int AF32>
__global__ __launch_bounds__(256)
void gemm_mfma(const void* __restrict__ Av, const bf16* __restrict__ Bt,
               void* __restrict__ Cv, void* __restrict__ Cv2,
               const float* __restrict__ emb, int Kn, int lda, int ldb, int ldc)
{
  constexpr int MI  = BM/32;         // 16-row tiles per wave
  constexpr int ITA = BM/32;         // A GLDS staging calls
  __shared__ bf16 As[(size_t)BM*64];
  __shared__ bf16 Bs[128*64];

  const int tid  = threadIdx.x;
  const int lane = tid & 63;
  const int w    = tid >> 6;
  const int col  = lane & 15, quad = lane >> 4;
  const int wr   = w >> 1, wc = w & 1;
  const size_t m0 = (size_t)blockIdx.y * BM;
  const size_t n0 = (size_t)blockIdx.x * 128;

  // B staging sources (pre-swizzled global)
  const bf16* bg[4];
  #pragma unroll
  for (int it = 0; it < 4; it++) {
    int c = tid + it*256, row = c >> 3, seg = c & 7;
    bg[it] = Bt + (n0 + row)*ldb + (size_t)((seg ^ (row & 7))*8);
  }
  // A staging
  const bf16* ag[ITA];
  const float* asrc = nullptr;
  int arow = 0;
  if constexpr (AF32) {
    arow = tid >> 2;
    const int aseg = tid & 3;
    asrc = (const float*)Av + (m0 + arow)*lda + aseg*16;
  } else {
    #pragma unroll
    for (int it = 0; it < ITA; it++) {
      int c = tid + it*256, row = c >> 3, seg = c & 7;
      ag[it] = (const bf16*)Av + (m0 + row)*lda + (size_t)((seg ^ (row & 7))*8);
    }
  }

  float4v acc[MI][4];
  #pragma unroll
  for (int i=0;i<MI;i++)
    #pragma unroll
    for (int j=0;j<4;j++) acc[i][j] = (float4v){0.f,0.f,0.f,0.f};

  for (int k0 = 0; k0 < Kn; k0 += 64) {
    #pragma unroll
    for (int it = 0; it < 4; it++)
      GLDS16(bg[it] + k0, Bs + (size_t)(tid + it*256)*8);
    if constexpr (AF32) {
      const int aseg = tid & 3;
      float4 f0 = *(const float4*)(asrc + k0);
      float4 f1 = *(const float4*)(asrc + k0 + 4);
      float4 f2 = *(const float4*)(asrc + k0 + 8);
      float4 f3 = *(const float4*)(asrc + k0 + 12);
      short8 h0, h1;
      h0[0]=(short)f2bf(f0.x); h0[1]=(short)f2bf(f0.y);
      h0[2]=(short)f2bf(f0.z); h0[3]=(short)f2bf(f0.w);
      h0[4]=(short)f2bf(f1.x); h0[5]=(short)f2bf(f1.y);
      h0[6]=(short)f2bf(f1.z); h0[7]=(short)f2bf(f1.w);
      h1[0]=(short)f2bf(f2.x); h1[1]=(short)f2bf(f2.y);
      h1[2]=(short)f2bf(f2.z); h1[3]=(short)f2bf(f2.w);
      h1[4]=(short)f2bf(f3.x); h1[5]=(short)f2bf(f3.y);
      h1[6]=(short)f2bf(f3.z); h1[7]=(short)f2bf(f3.w);
      const int sl0 = (aseg*2) ^ (arow & 7), sl1 = (aseg*2+1) ^ (arow & 7);
      *(short8*)&As[arow*64 + sl0*8] = h0;
      *(short8*)&As[arow*64 + sl1*8] = h1;
    } else {
      #pragma unroll
      for (int it = 0; it < ITA; it++)
        GLDS16(ag[it] + k0, As + (size_t)(tid + it*256)*8);
    }
    __syncthreads();

    short8 af[MI][2], bfr[4][2];
    #pragma unroll
    for (int i=0;i<MI;i++) {
      const int ar = wr*(BM/2) + i*16 + col;
      #pragma unroll
      for (int k2=0;k2<2;k2++)
        af[i][k2] = *(const short8*)&As[ar*64 + ((k2*4+quad)^(ar&7))*8];
    }
    #pragma unroll
    for (int j=0;j<4;j++) {
      const int br = wc*64 + j*16 + col;
      #pragma unroll
      for (int k2=0;k2<2;k2++)
        bfr[j][k2] = *(const short8*)&Bs[br*64 + ((k2*4+quad)^(br&7))*8];
    }

    #pragma unroll
    for (int k2=0;k2<2;k2++)
      #pragma unroll
      for (int i=0;i<MI;i++)
        #pragma unroll
        for (int j=0;j<4;j++)
          acc[i][j] = __builtin_amdgcn_mfma_f32_16x16x32_bf16(af[i][k2], bfr[j][k2], acc[i][j], 0,0,0);
    __syncthreads();
  }

  // ---- epilogues ----
  if constexpr (CMODE == 0) {
    #pragma unroll
    for (int i=0;i<MI;i++) {
      const size_t row0 = m0 + wr*(BM/2) + i*16 + quad*4;
      #pragma unroll
      for (int j=0;j<4;j++) {
        const int c = (int)n0 + wc*64 + j*16 + col;
        #pragma unroll
        for (int r=0;r<4;r++)
          ((float*)Cv)[(row0+r)*ldc + c] = acc[i][j][r];
      }
    }
    return;
  }

  constexpr int RBASE = (CMODE == 5) ? 384 : 768;   // rope/split boundary
  if ((int)n0 < RBASE) {
    // low region
    #pragma unroll
    for (int i=0;i<MI;i++) {
      const size_t row0 = m0 + wr*(BM/2) + i*16 + quad*4;
      #pragma unroll
      for (int j=0;j<4;j++) {
        const int c = (int)n0 + wc*64 + j*16 + col;
        #pragma unroll
        for (int r=0;r<4;r++) {
          const float v = acc[i][j][r];
          if constexpr (CMODE == 5)
            ((bf16*)Cv)[(row0+r)*384 + c] = __float2bfloat16(v);
          else // 3,4: head-split bf16 (k_c / q_c -> dims 0..63)
            ((bf16*)Cv)[(row0+r)*HID_ + (c>>6)*HD_ + (c&63)] = __float2bfloat16(v);
        }
      }
    }
  } else if constexpr (CMODE == 3) {
    // V transposed into Vtg[b][h][d][s]; 4 rows are s-contiguous -> short4
    #pragma unroll
    for (int i=0;i<MI;i++) {
      const size_t row0 = m0 + wr*(BM/2) + i*16 + quad*4;
      const int bb = (int)(row0 >> 11), s = (int)(row0 & (S_-1));
      #pragma unroll
      for (int j=0;j<4;j++) {
        const int cv = (int)n0 - 768 + wc*64 + j*16 + col;
        const int hh = cv >> 7, d = cv & 127;
        short4v st;
        #pragma unroll
        for (int r=0;r<4;r++) st[r] = (short)f2bf(acc[i][j][r]);
        *(short4v*)((unsigned short*)Cv2 +
            ((size_t)(bb*H_+hh)*HD_ + d)*S_ + s) = st;
      }
    }
  } else {
    // rope region (CMODE 5 -> Kf, CMODE 4 -> Qf): pairs (j, j+2)
    const int hh = (((int)n0 - RBASE) >> 6) + wc;
    #pragma unroll
    for (int i=0;i<MI;i++) {
      const size_t row0 = m0 + wr*(BM/2) + i*16 + quad*4;
      #pragma unroll
      for (int j=0;j<2;j++) {
        const int idim = j*16 + col;          // 0..31
        #pragma unroll
        for (int r=0;r<4;r++) {
          const size_t row = row0 + r;
          const int s = (int)(row & (S_-1));
          const float sn = emb[(size_t)s*ROT_ + idim];
          const float cs = emb[(size_t)s*ROT_ + 32 + idim];
          const float x1 = acc[i][j][r], x2 = acc[i][j+2][r];
          bf16* dst = (bf16*)Cv2 + (row*H_ + hh)*HD_ + 64 + idim;
          dst[0]  = __float2bfloat16(x1*cs - x2*sn);
          dst[32] = __float2bfloat16(x1*sn + x2*cs);
        }
      }
    }
  }
}

// ---------------------------------------------------------------------------
// MFMA flash attention, causal. Block = 4 waves = 64 queries; 64-key blocks.
// Swapped QK^T (lane owns one q), T14 reg prefetch, bulk/diagonal split
// (bulk iters are mask-free), defer-max (T13, THR=11 in log2 domain),
// exp2-domain softmax.
// ---------------------------------------------------------------------------
#define KSTR 136   // 128+8  (272B rows, 16B aligned)
#define VSTR 72    // 64+8   (144B rows, 16B aligned)
#define PSTR 72

__global__ __launch_bounds__(256)
void attn_mfma(const bf16* __restrict__ Qf, const bf16* __restrict__ Kf,
               const bf16* __restrict__ Vtg, bf16* __restrict__ at)
{
  const int qt = (S_/64 - 1) - (int)(blockIdx.x / (B_*H_));   // long-first
  const int bh = blockIdx.x % (B_*H_);
  const int h  = bh % H_, b = bh / H_;
  const int tid  = threadIdx.x;
  const int w    = tid >> 6;
  const int lane = tid & 63;
  const int col  = lane & 15;
  const int quad = lane >> 4;

  __shared__ unsigned short Ks[64*KSTR];       // 17408 B
  __shared__ unsigned short Vt[128*VSTR];      // 18432 B
  __shared__ unsigned short Ps[4][16*PSTR];    //  9216 B

  const int q0  = qt * 64;
  const int q0w = q0 + w*16;

  const unsigned short* Kb = (const unsigned short*)Kf +
      ((size_t)b*S_*H_ + h)*HD_;
  const unsigned short* Vb = (const unsigned short*)Vtg +
      (size_t)(b*H_ + h)*HD_*S_;

  const unsigned short* kgp[4]; unsigned short* kdst[4];
  const unsigned short* vgp[4]; unsigned short* vdst[4];
  #pragma unroll
  for (int it = 0; it < 4; it++) {
    int c = tid + it*256;
    int key = c >> 4, doff = (c & 15)*8;
    kgp[it]  = Kb + (size_t)key*HID_ + doff;
    kdst[it] = &Ks[key*KSTR + doff];
    int d = c >> 3, kg = (c & 7)*8;
    vgp[it]  = Vb + (size_t)d*S_ + kg;
    vdst[it] = &Vt[d*VSTR + kg];
  }

  // Q fragments (B-operand of swapped QK^T)
  short8 qf[4];
  {
    const unsigned short* qrow = (const unsigned short*)Qf +
        ((size_t)((size_t)b*S_ + q0w + col)*H_ + h)*HD_;
    #pragma unroll
    for (int kk = 0; kk < 4; kk++)
      qf[kk] = *(const short8*)(qrow + kk*32 + quad*8);
  }

  float4v O[8];
  #pragma unroll
  for (int t=0;t<8;t++) O[t] = (float4v){0.f,0.f,0.f,0.f};
  float m_ln = -1e30f, l_ln = 0.f;

  // scale folded into log2 domain: exp(x*scale) = exp2(x*scale*log2e)
  const float scale2 = 0.08838834764831845f * 1.4426950408889634f;

  // prologue: load tile 0 into regs
  short8 kr[4], vr[4];
  #pragma unroll
  for (int it = 0; it < 4; it++) {
    kr[it] = *(const short8*)kgp[it];
    vr[it] = *(const short8*)vgp[it];
  }

  for (int kb = 0; kb <= qt; kb++) {
    const int k0 = kb * 64;
    const bool diag = (kb == qt);

    #pragma unroll
    for (int it = 0; it < 4; it++) *(short8*)kdst[it] = kr[it];
    #pragma unroll
    for (int it = 0; it < 4; it++) *(short8*)vdst[it] = vr[it];
    __syncthreads();

    if (!diag) {   // T14: prefetch next tile; latency hides under compute
      const size_t kn = (size_t)(k0 + 64);
      #pragma unroll
      for (int it = 0; it < 4; it++) {
        kr[it] = *(const short8*)(kgp[it] + kn*HID_);
        vr[it] = *(const short8*)(vgp[it] + kn);
      }
    }

    // ---- swapped QK^T: D[key][q], lane q = q0w+col ----
    float4v Sf[4];
    #pragma unroll
    for (int tc=0;tc<4;tc++) Sf[tc] = (float4v){0.f,0.f,0.f,0.f};
    __builtin_amdgcn_s_setprio(1);
    if (!diag) {
      #pragma unroll
      for (int tc = 0; tc < 4; tc++)
        #pragma unroll
        for (int kk = 0; kk < 4; kk++) {
          short8 kfrag = *(const short8*)&Ks[(16*tc+col)*KSTR + 32*kk + quad*8];
          Sf[tc] = __builtin_amdgcn_mfma_f32_16x16x32_bf16(kfrag, qf[kk], Sf[tc], 0,0,0);
        }
    } else {
      #pragma unroll
      for (int tc = 0; tc < 4; tc++) {
        if (tc <= w) {
          #pragma unroll
          for (int kk = 0; kk < 4; kk++) {
            short8 kfrag = *(const short8*)&Ks[(16*tc+col)*KSTR + 32*kk + quad*8];
            Sf[tc] = __builtin_amdgcn_mfma_f32_16x16x32_bf16(kfrag, qf[kk], Sf[tc], 0,0,0);
          }
        }
      }
    }
    __builtin_amdgcn_s_setprio(0);

    // ---- softmax (log2 domain), lane-local 16 keys ----
    float sv[4][4];
    float pmax = -3.0e38f;
    if (!diag) {
      #pragma unroll
      for (int tc = 0; tc < 4; tc++)
        #pragma unroll
        for (int r = 0; r < 4; r++) {
          float s = Sf[tc][r] * scale2;
          sv[tc][r] = s;
          pmax = fmaxf(pmax, s);
        }
    } else {
      const int qrel = w*16 + col;
      #pragma unroll
      for (int tc = 0; tc < 4; tc++)
        #pragma unroll
        for (int r = 0; r < 4; r++) {
          float s = Sf[tc][r] * scale2;
          if (tc*16 + quad*4 + r > qrel) s = -3.0e38f;
          sv[tc][r] = s;
          pmax = fmaxf(pmax, s);
        }
    }
    pmax = fmaxf(pmax, __shfl_xor(pmax, 16));
    pmax = fmaxf(pmax, __shfl_xor(pmax, 32));

    if (__all(pmax <= m_ln + 11.0f)) {        // T13 defer-max: no rescale
      float lt = 0.f;
      #pragma unroll
      for (int tc = 0; tc < 4; tc++)
        #pragma unroll
        for (int r = 0; r < 4; r++) {
          sv[tc][r] = exp2f(sv[tc][r] - m_ln);
          lt += sv[tc][r];
        }
      lt += __shfl_xor(lt, 16);
      lt += __shfl_xor(lt, 32);
      l_ln += lt;
    } else {
      const float mnew = fmaxf(m_ln, pmax);
      float lt = 0.f;
      #pragma unroll
      for (int tc = 0; tc < 4; tc++)
        #pragma unroll
        for (int r = 0; r < 4; r++) {
          sv[tc][r] = exp2f(sv[tc][r] - mnew);
          lt += sv[tc][r];
        }
      lt += __shfl_xor(lt, 16);
      lt += __shfl_xor(lt, 32);
      const float al = exp2f(m_ln - mnew);
      l_ln = l_ln * al + lt;
      m_ln = mnew;
      float alr[4];
      #pragma unroll
      for (int r = 0; r < 4; r++) alr[r] = __shfl(al, quad*4 + r);
      #pragma unroll
      for (int t = 0; t < 8; t++)
        #pragma unroll
        for (int r = 0; r < 4; r++) O[t][r] *= alr[r];
    }

    // write P row q=col: one ds_write_b64 per tc
    #pragma unroll
    for (int tc = 0; tc < 4; tc++) {
      short4v pw;
      pw[0] = (short)f2bf(sv[tc][0]); pw[1] = (short)f2bf(sv[tc][1]);
      pw[2] = (short)f2bf(sv[tc][2]); pw[3] = (short)f2bf(sv[tc][3]);
      *(short4v*)&Ps[w][col*PSTR + tc*16 + quad*4] = pw;
    }

    // ---- PV: P(16x64) @ V(64x128) ----
    __builtin_amdgcn_s_setprio(1);
    if (!diag) {
      #pragma unroll
      for (int ks = 0; ks < 2; ks++) {
        short8 pf = *(const short8*)&Ps[w][col*PSTR + 32*ks + quad*8];
        #pragma unroll
        for (int t = 0; t < 8; t++) {
          short8 vf = *(const short8*)&Vt[(16*t + col)*VSTR + 32*ks + quad*8];
          O[t] = __builtin_amdgcn_mfma_f32_16x16x32_bf16(pf, vf, O[t], 0,0,0);
        }
      }
    } else {
      #pragma unroll
      for (int ks = 0; ks < 2; ks++) {
        if (ks == 0 || w >= 2) {
          short8 pf = *(const short8*)&Ps[w][col*PSTR + 32*ks + quad*8];
          #pragma unroll
          for (int t = 0; t < 8; t++) {
            short8 vf = *(const short8*)&Vt[(16*t + col)*VSTR + 32*ks + quad*8];
            O[t] = __builtin_amdgcn_mfma_f32_16x16x32_bf16(pf, vf, O[t], 0,0,0);
          }
        }
      }
    }
    __builtin_amdgcn_s_setprio(0);
    __syncthreads();
  }

  // epilogue: rows q = quad*4+r need l of those rows
  float lr[4];
  #pragma unroll
  for (int r = 0; r < 4; r++) lr[r] = __shfl(l_ln, quad*4 + r);
  #pragma unroll
  for (int r = 0; r < 4; r++) {
    const float linv = 1.f / lr[r];
    const size_t mq = (size_t)b*S_ + q0w + quad*4 + r;
    bf16* dst = at + mq*HID_ + h*HD_ + col;
    #pragma unroll
    for (int t = 0; t < 8; t++)
      dst[16*t] = __float2bfloat16(O[t][r] * linv);
  }
}

extern "C" void kernel_launch(void* const* d_in, const int* in_sizes, int n_in,
                              void* d_out, int out_size, void* d_ws, size_t ws_size,
                              hipStream_t stream)
{
  float* out = (float*)d_out;

  // Size guard tripwire.
  static const int sz_dict[10] = {6291456,131072,294912,294912,147456,
                                  147456,294912,1179648,147456,2359296};
  int bad = -1;
  if (n_in < 10) bad = 15;
  else {
    for (int i = 0; i < 10; i++)
      if (in_sizes[i] != sz_dict[i]) { bad = i; break; }
  }
  if (bad >= 0) {
    float v = 1.0e6f * (float)(1 + bad);
    if (bad < 10) v += (float)(in_sizes[bad] % 1000000);
    fillf_k<<<(out_size + 255)/256, 256, 0, stream>>>(out, v, out_size);
    return;
  }

  const float* hidden = (const float*)d_in[0];
  const float* emb    = (const float*)d_in[1];
  const float* Wkvd   = (const float*)d_in[2];
  const float* Wqd    = (const float*)d_in[3];
  const float* Wku    = (const float*)d_in[4];
  const float* Wqu    = (const float*)d_in[5];
  const float* Wvu    = (const float*)d_in[6];
  const float* Wrk    = (const float*)d_in[7];
  const float* Wrq    = (const float*)d_in[8];
  const float* Wo     = (const float*)d_in[9];

  // --- workspace carve (256B aligned each) ---
  char* wp = (char*)d_ws;
  size_t used = 0;
  auto alloc = [&](size_t bytes) -> void* {
    void* p = wp + used;
    used += (bytes + 255) & ~(size_t)255;
    return p;
  };
  bf16*  dout  = (bf16*)alloc((size_t)M_*384*2);         // [kvd|qd] (M,384)
  bf16*  Kf    = (bf16*)alloc((size_t)M_*HID_*2);        // [m][h][128] bf16
  bf16*  Qf    = (bf16*)alloc((size_t)M_*HID_*2);
  bf16*  Vtg   = (bf16*)alloc((size_t)B_*H_*HD_*S_*2);   // [b][h][d][s] bf16
  bf16*  at    = (bf16*)alloc((size_t)M_*HID_*2);
  bf16*  WdkrT = (bf16*)alloc((size_t)1152*HID_*2);      // [WkvdT;WqdT;WrkT]
  bf16*  WkvuT = (bf16*)alloc((size_t)2304*LAT_*2);      // [WkuT;WvuT]
  bf16*  WqurT = (bf16*)alloc((size_t)1536*LAT_*2);      // [WquT;WrqT]
  bf16*  WoT   = (bf16*)alloc((size_t)HID_*HID_*2);

  if (used > ws_size) {   // workspace tripwire
    fillf_k<<<(out_size + 255)/256, 256, 0, stream>>>(out, 5.0e7f, out_size);
    return;
  }

  // --- weight packs: 2 batched launches (shared K per launch) ---
  packT4_k<<<dim3(48,48,4), 256, 0, stream>>>(
      Wkvd, Wqd, Wrk, Wo,
      WdkrT, WdkrT + (size_t)192*HID_, WdkrT + (size_t)384*HID_, WoT,
      HID_, LAT_, LAT_, H_*ROT_, HID_);
  packT4_k<<<dim3(6,48,4), 256, 0, stream>>>(
      Wku, Wvu, Wqu, Wrq,
      WkvuT, WkvuT + (size_t)768*LAT_, WqurT, WqurT + (size_t)768*LAT_,
      LAT_, H_*ROT_, HID_, H_*ROT_, H_*ROT_);

  // --- fused MFMA GEMMs ---
  // G1: hidden(fp32) @ [Wkvd;Wqd;Wrk]^T -> dout | rope-K into Kf[64..127]
  gemm_mfma<5,64,1><<<dim3(9, M_/64),  256, 0, stream>>>(hidden, WdkrT, dout, Kf, emb, HID_, HID_, HID_, 0);
  // G2: kvd @ [Wku;Wvu]^T -> Kf head-split (k_c) | V transposed -> Vtg
  gemm_mfma<3,64,0><<<dim3(18, M_/64), 256, 0, stream>>>(dout,     WkvuT, Kf, Vtg, emb, LAT_, 384, LAT_, 0);
  // G3: qd @ [Wqu;Wrq]^T -> Qf head-split (q_c) | rope-Q into Qf[64..127]
  gemm_mfma<4,64,0><<<dim3(12, M_/64), 256, 0, stream>>>(dout+192, WqurT, Qf, Qf,  emb, LAT_, 384, LAT_, 0);

  // MFMA flash attention (64-query blocks, 64-key tiles)
  attn_mfma<<<B_*H_*(S_/64), 256, 0, stream>>>(Qf, Kf, Vtg, at);

  // out = at @ Wo
  gemm_mfma<0,128,0><<<dim3(HID_/128, M_/128), 256, 0, stream>>>(at, WoT, out, nullptr, emb, HID_, HID_, HID_, HID_);
}

// Round 5
// 261.926 us; speedup vs baseline: 4.6305x; 1.0174x over previous
//
#include <hip/hip_runtime.h>
#include <hip/hip_bf16.h>

#define B_ 2
#define S_ 2048
#define HID_ 1536
#define H_ 12
#define HD_ 128
#define LAT_ 192
#define ROT_ 64
#define M_ (B_*S_)         // 4096
#define NTILE_ (B_*H_*(S_/64))   // 768 attn q-tiles

typedef __hip_bfloat16 bf16;

using short8  = __attribute__((ext_vector_type(8))) short;
using short4v = __attribute__((ext_vector_type(4))) short;
using float4v = __attribute__((ext_vector_type(4))) float;

__device__ __forceinline__ unsigned short f2bf(float f) {
  __hip_bfloat16 h = __float2bfloat16(f);
  unsigned short u; __builtin_memcpy(&u, &h, 2); return u;
}

// async global->LDS, 16B per lane (wave-uniform LDS base + lane*16)
#define GLDS16(gp, lp) __builtin_amdgcn_global_load_lds( \
    (__attribute__((address_space(1))) void*)(size_t)(gp), \
    (__attribute__((address_space(3))) void*)(lp), 16, 0, 0)

__global__ __launch_bounds__(256)
void fillf_k(float* __restrict__ out, float v, int n)
{
  int i = blockIdx.x*256 + threadIdx.x;
  if (i < n) out[i] = v;
}

// ---------------------------------------------------------------------------
// Batched weight transpose+pack (z=0..3): W(K,N) fp32 -> Wt(N,K) bf16.
// z=4: grid-stride fp32->bf16 elementwise pack of hidden (packA).
// ---------------------------------------------------------------------------
__global__ __launch_bounds__(256)
void packT5_k(const float* __restrict__ s0, const float* __restrict__ s1,
              const float* __restrict__ s2, const float* __restrict__ s3,
              bf16* __restrict__ d0, bf16* __restrict__ d1,
              bf16* __restrict__ d2, bf16* __restrict__ d3,
              int Kn, int N0, int N1, int N2, int N3,
              const float* __restrict__ hsrc, bf16* __restrict__ hdst)
{
  if (blockIdx.z == 4) {               // packA branch (grid-stride float4)
    const int nblk = gridDim.x * gridDim.y;
    const int flatb = blockIdx.y * gridDim.x + blockIdx.x;
    const float4* in4 = (const float4*)hsrc;
    for (int i = flatb*256 + threadIdx.x; i < M_*HID_/4; i += nblk*256) {
      float4 v = in4[i];
      short4v o;
      o[0] = (short)f2bf(v.x); o[1] = (short)f2bf(v.y);
      o[2] = (short)f2bf(v.z); o[3] = (short)f2bf(v.w);
      *(short4v*)&hdst[i*4] = o;
    }
    return;
  }
  const float* W; bf16* Wt; int Nn;
  switch (blockIdx.z) {
    case 0:  W = s0; Wt = d0; Nn = N0; break;
    case 1:  W = s1; Wt = d1; Nn = N1; break;
    case 2:  W = s2; Wt = d2; Nn = N2; break;
    default: W = s3; Wt = d3; Nn = N3; break;
  }
  const int kb = blockIdx.x*32, nb = blockIdx.y*32;
  if (nb >= Nn) return;
  __shared__ float t[32][33];
  const int tx = threadIdx.x & 31, ty = threadIdx.x >> 5;
  #pragma unroll
  for (int i = 0; i < 4; i++)
    t[ty+8*i][tx] = W[(size_t)(kb+ty+8*i)*Nn + nb + tx];
  __syncthreads();
  #pragma unroll
  for (int i = 0; i < 4; i++)
    Wt[(size_t)(nb + ty + 8*i)*Kn + kb + tx] = __float2bfloat16(t[tx][ty+8*i]);
}

// ---------------------------------------------------------------------------
// MFMA bf16 GEMM: C(M,N) = A(M,K) @ Bt(N,K)^T.  128x128 tile, BK=64,
// 4 waves 2x2, each wave 64x64.  LDS staged via global_load_lds with
// XOR-swizzled GLOBAL source (T2 both-sides rule).
// CMODE epilogues (regions block-uniform; boundaries on 128 multiples):
//   0: fp32 linear (ldc)                                 [out = at @ Wo]
//   5: c<384 -> dout bf16 (ldc 384); else ROPE -> Kf dims 64..127
//   6: c<768 -> Kf k_c head-split; <2304 -> V transposed -> Vtg;
//      <3072 -> Qf q_c head-split; else ROPE -> Qf dims 64..127
//      (CMODE 6 selects A/B base by n0: >=2304 uses Av2/Bt2, rows n0-2304)
// Rope pairing is lane-local: acc[i][j] (d=j*16+col<32) pairs acc[i][j+2].
// ---------------------------------------------------------------------------
template<int CMODE, int BM>
__global__ __launch_bounds__(256)
void gemm_mfma(const bf16* __restrict__ Av, const bf16* __restrict__ Btp,
               const bf16* __restrict__ Av2, const bf16* __restrict__ Bt2,
               void* __restrict__ Cv, void* __restrict__ Cv2,
               void* __restrict__ Cv3,
               const float* __restrict__ emb, int Kn, int lda, int ldb, int ldc)
{
  constexpr int MI  = BM/32;         // 16-row tiles per wave
  constexpr int ITA = BM/32;         // A GLDS staging calls
  __shared__ bf16 As[(size_t)BM*64];
  __shared__ bf16 Bs[128*64];

  const int tid  = threadIdx.x;
  const int lane = tid & 63;
  const int w    = tid >> 6;
  const int col  = lane & 15, quad = lane >> 4;
  const int wr   = w >> 1, wc = w & 1;
  const size_t m0 = (size_t)blockIdx.y * BM;
  const size_t n0 = (size_t)blockIdx.x * 128;

  const bf16* Abase = Av;
  const bf16* Bt    = Btp;
  size_t nrow0 = n0;
  if constexpr (CMODE == 6) {
    if ((int)n0 >= 2304) { Abase = Av2; Bt = Bt2; nrow0 = n0 - 2304; }
  }

  const bf16* bg[4];
  #pragma unroll
  for (int it = 0; it < 4; it++) {
    int c = tid + it*256, row = c >> 3, seg = c & 7;
    bg[it] = Bt + (nrow0 + row)*ldb + (size_t)((seg ^ (row & 7))*8);
  }
  const bf16* ag[ITA];
  #pragma unroll
  for (int it = 0; it < ITA; it++) {
    int c = tid + it*256, row = c >> 3, seg = c & 7;
    ag[it] = Abase + (m0 + row)*lda + (size_t)((seg ^ (row & 7))*8);
  }

  float4v acc[MI][4];
  #pragma unroll
  for (int i=0;i<MI;i++)
    #pragma unroll
    for (int j=0;j<4;j++) acc[i][j] = (float4v){0.f,0.f,0.f,0.f};

  for (int k0 = 0; k0 < Kn; k0 += 64) {
    #pragma unroll
    for (int it = 0; it < 4; it++)
      GLDS16(bg[it] + k0, Bs + (size_t)(tid + it*256)*8);
    #pragma unroll
    for (int it = 0; it < ITA; it++)
      GLDS16(ag[it] + k0, As + (size_t)(tid + it*256)*8);
    __syncthreads();

    short8 af[MI][2], bfr[4][2];
    #pragma unroll
    for (int i=0;i<MI;i++) {
      const int ar = wr*(BM/2) + i*16 + col;
      #pragma unroll
      for (int k2=0;k2<2;k2++)
        af[i][k2] = *(const short8*)&As[ar*64 + ((k2*4+quad)^(ar&7))*8];
    }
    #pragma unroll
    for (int j=0;j<4;j++) {
      const int br = wc*64 + j*16 + col;
      #pragma unroll
      for (int k2=0;k2<2;k2++)
        bfr[j][k2] = *(const short8*)&Bs[br*64 + ((k2*4+quad)^(br&7))*8];
    }

    #pragma unroll
    for (int k2=0;k2<2;k2++)
      #pragma unroll
      for (int i=0;i<MI;i++)
        #pragma unroll
        for (int j=0;j<4;j++)
          acc[i][j] = __builtin_amdgcn_mfma_f32_16x16x32_bf16(af[i][k2], bfr[j][k2], acc[i][j], 0,0,0);
    __syncthreads();
  }

  // ---- epilogues ----
  if constexpr (CMODE == 0) {
    #pragma unroll
    for (int i=0;i<MI;i++) {
      const size_t row0 = m0 + wr*(BM/2) + i*16 + quad*4;
      #pragma unroll
      for (int j=0;j<4;j++) {
        const int c = (int)n0 + wc*64 + j*16 + col;
        #pragma unroll
        for (int r=0;r<4;r++)
          ((float*)Cv)[(row0+r)*ldc + c] = acc[i][j][r];
      }
    }
    return;
  }

  if constexpr (CMODE == 5) {
    if ((int)n0 < 384) {
      #pragma unroll
      for (int i=0;i<MI;i++) {
        const size_t row0 = m0 + wr*(BM/2) + i*16 + quad*4;
        #pragma unroll
        for (int j=0;j<4;j++) {
          const int c = (int)n0 + wc*64 + j*16 + col;
          #pragma unroll
          for (int r=0;r<4;r++)
            ((bf16*)Cv)[(row0+r)*384 + c] = __float2bfloat16(acc[i][j][r]);
        }
      }
    } else {
      // rope -> Kf dims 64..127
      const int hh = (((int)n0 - 384) >> 6) + wc;
      #pragma unroll
      for (int i=0;i<MI;i++) {
        const size_t row0 = m0 + wr*(BM/2) + i*16 + quad*4;
        #pragma unroll
        for (int j=0;j<2;j++) {
          const int idim = j*16 + col;
          #pragma unroll
          for (int r=0;r<4;r++) {
            const size_t row = row0 + r;
            const int s = (int)(row & (S_-1));
            const float sn = emb[(size_t)s*ROT_ + idim];
            const float cs = emb[(size_t)s*ROT_ + 32 + idim];
            const float x1 = acc[i][j][r], x2 = acc[i][j+2][r];
            bf16* dst = (bf16*)Cv2 + (row*H_ + hh)*HD_ + 64 + idim;
            dst[0]  = __float2bfloat16(x1*cs - x2*sn);
            dst[32] = __float2bfloat16(x1*sn + x2*cs);
          }
        }
      }
    }
    return;
  }

  // CMODE == 6
  if ((int)n0 < 768) {
    // k_c head-split into Kf dims 0..63
    #pragma unroll
    for (int i=0;i<MI;i++) {
      const size_t row0 = m0 + wr*(BM/2) + i*16 + quad*4;
      #pragma unroll
      for (int j=0;j<4;j++) {
        const int c = (int)n0 + wc*64 + j*16 + col;
        #pragma unroll
        for (int r=0;r<4;r++)
          ((bf16*)Cv)[(row0+r)*HID_ + (c>>6)*HD_ + (c&63)] = __float2bfloat16(acc[i][j][r]);
      }
    }
  } else if ((int)n0 < 2304) {
    // V transposed into Vtg[b][h][d][s]; 4 rows s-contiguous -> short4
    #pragma unroll
    for (int i=0;i<MI;i++) {
      const size_t row0 = m0 + wr*(BM/2) + i*16 + quad*4;
      const int bb = (int)(row0 >> 11), s = (int)(row0 & (S_-1));
      #pragma unroll
      for (int j=0;j<4;j++) {
        const int cv = (int)n0 - 768 + wc*64 + j*16 + col;
        const int hh = cv >> 7, d = cv & 127;
        short4v st;
        #pragma unroll
        for (int r=0;r<4;r++) st[r] = (short)f2bf(acc[i][j][r]);
        *(short4v*)((unsigned short*)Cv2 +
            ((size_t)(bb*H_+hh)*HD_ + d)*S_ + s) = st;
      }
    }
  } else if ((int)n0 < 3072) {
    // q_c head-split into Qf dims 0..63
    #pragma unroll
    for (int i=0;i<MI;i++) {
      const size_t row0 = m0 + wr*(BM/2) + i*16 + quad*4;
      #pragma unroll
      for (int j=0;j<4;j++) {
        const int c = (int)n0 - 2304 + wc*64 + j*16 + col;
        #pragma unroll
        for (int r=0;r<4;r++)
          ((bf16*)Cv3)[(row0+r)*HID_ + (c>>6)*HD_ + (c&63)] = __float2bfloat16(acc[i][j][r]);
      }
    }
  } else {
    // rope -> Qf dims 64..127
    const int hh = (((int)n0 - 3072) >> 6) + wc;
    #pragma unroll
    for (int i=0;i<MI;i++) {
      const size_t row0 = m0 + wr*(BM/2) + i*16 + quad*4;
      #pragma unroll
      for (int j=0;j<2;j++) {
        const int idim = j*16 + col;
        #pragma unroll
        for (int r=0;r<4;r++) {
          const size_t row = row0 + r;
          const int s = (int)(row & (S_-1));
          const float sn = emb[(size_t)s*ROT_ + idim];
          const float cs = emb[(size_t)s*ROT_ + 32 + idim];
          const float x1 = acc[i][j][r], x2 = acc[i][j+2][r];
          bf16* dst = (bf16*)Cv3 + (row*H_ + hh)*HD_ + 64 + idim;
          dst[0]  = __float2bfloat16(x1*cs - x2*sn);
          dst[32] = __float2bfloat16(x1*sn + x2*cs);
        }
      }
    }
  }
}

// ---------------------------------------------------------------------------
// MFMA flash attention, causal. 4 waves = 64 queries/tile; 64-key blocks.
// DYNAMIC QUEUE: grid 512 blocks (2/CU) pull q-tiles heavy-first from a
// global atomic counter -> LPT load balance (static 768-grid was fully
// co-resident with a 2x per-CU skew).  Swapped QK^T, T14 reg prefetch,
// bulk/diagonal split, defer-max (T13), exp2-domain softmax.
// ---------------------------------------------------------------------------
#define KSTR 136   // 128+8  (272B rows, 16B aligned)
#define VSTR 72    // 64+8   (144B rows, 16B aligned)
#define PSTR 72

__global__ __launch_bounds__(256)
void attn_mfma(const bf16* __restrict__ Qf, const bf16* __restrict__ Kf,
               const bf16* __restrict__ Vtg, bf16* __restrict__ at,
               int* __restrict__ qcnt)
{
  const int tid  = threadIdx.x;
  const int w    = tid >> 6;
  const int lane = tid & 63;
  const int col  = lane & 15;
  const int quad = lane >> 4;

  __shared__ unsigned short Ks[64*KSTR];       // 17408 B
  __shared__ unsigned short Vt[128*VSTR];      // 18432 B
  __shared__ unsigned short Ps[4][16*PSTR];    //  9216 B
  __shared__ int sidx;

  const float scale2 = 0.08838834764831845f * 1.4426950408889634f;

  for (;;) {
    if (tid == 0) sidx = atomicAdd(qcnt, 1);
    __syncthreads();
    const int my = sidx;
    __syncthreads();
    if (my >= NTILE_) return;

    const int qt = (S_/64 - 1) - my/24;        // heavy-first
    const int bh = my % 24;
    const int h  = bh % H_, b = bh / H_;
    const int q0w = qt*64 + w*16;

    const unsigned short* Kb = (const unsigned short*)Kf +
        ((size_t)b*S_*H_ + h)*HD_;
    const unsigned short* Vb = (const unsigned short*)Vtg +
        (size_t)(b*H_ + h)*HD_*S_;

    const unsigned short* kgp[4]; unsigned short* kdst[4];
    const unsigned short* vgp[4]; unsigned short* vdst[4];
    #pragma unroll
    for (int it = 0; it < 4; it++) {
      int c = tid + it*256;
      int key = c >> 4, doff = (c & 15)*8;
      kgp[it]  = Kb + (size_t)key*HID_ + doff;
      kdst[it] = &Ks[key*KSTR + doff];
      int d = c >> 3, kg = (c & 7)*8;
      vgp[it]  = Vb + (size_t)d*S_ + kg;
      vdst[it] = &Vt[d*VSTR + kg];
    }

    short8 qf[4];
    {
      const unsigned short* qrow = (const unsigned short*)Qf +
          ((size_t)((size_t)b*S_ + q0w + col)*H_ + h)*HD_;
      #pragma unroll
      for (int kk = 0; kk < 4; kk++)
        qf[kk] = *(const short8*)(qrow + kk*32 + quad*8);
    }

    float4v O[8];
    #pragma unroll
    for (int t=0;t<8;t++) O[t] = (float4v){0.f,0.f,0.f,0.f};
    float m_ln = -1e30f, l_ln = 0.f;

    short8 kr[4], vr[4];
    #pragma unroll
    for (int it = 0; it < 4; it++) {
      kr[it] = *(const short8*)kgp[it];
      vr[it] = *(const short8*)vgp[it];
    }

    for (int kb = 0; kb <= qt; kb++) {
      const int k0 = kb * 64;
      const bool diag = (kb == qt);

      #pragma unroll
      for (int it = 0; it < 4; it++) *(short8*)kdst[it] = kr[it];
      #pragma unroll
      for (int it = 0; it < 4; it++) *(short8*)vdst[it] = vr[it];
      __syncthreads();

      if (!diag) {   // T14 prefetch
        const size_t kn = (size_t)(k0 + 64);
        #pragma unroll
        for (int it = 0; it < 4; it++) {
          kr[it] = *(const short8*)(kgp[it] + kn*HID_);
          vr[it] = *(const short8*)(vgp[it] + kn);
        }
      }

      float4v Sf[4];
      #pragma unroll
      for (int tc=0;tc<4;tc++) Sf[tc] = (float4v){0.f,0.f,0.f,0.f};
      __builtin_amdgcn_s_setprio(1);
      if (!diag) {
        #pragma unroll
        for (int tc = 0; tc < 4; tc++)
          #pragma unroll
          for (int kk = 0; kk < 4; kk++) {
            short8 kfrag = *(const short8*)&Ks[(16*tc+col)*KSTR + 32*kk + quad*8];
            Sf[tc] = __builtin_amdgcn_mfma_f32_16x16x32_bf16(kfrag, qf[kk], Sf[tc], 0,0,0);
          }
      } else {
        #pragma unroll
        for (int tc = 0; tc < 4; tc++) {
          if (tc <= w) {
            #pragma unroll
            for (int kk = 0; kk < 4; kk++) {
              short8 kfrag = *(const short8*)&Ks[(16*tc+col)*KSTR + 32*kk + quad*8];
              Sf[tc] = __builtin_amdgcn_mfma_f32_16x16x32_bf16(kfrag, qf[kk], Sf[tc], 0,0,0);
            }
          }
        }
      }
      __builtin_amdgcn_s_setprio(0);

      float sv[4][4];
      float pmax = -3.0e38f;
      if (!diag) {
        #pragma unroll
        for (int tc = 0; tc < 4; tc++)
          #pragma unroll
          for (int r = 0; r < 4; r++) {
            float s = Sf[tc][r] * scale2;
            sv[tc][r] = s;
            pmax = fmaxf(pmax, s);
          }
      } else {
        const int qrel = w*16 + col;
        #pragma unroll
        for (int tc = 0; tc < 4; tc++)
          #pragma unroll
          for (int r = 0; r < 4; r++) {
            float s = Sf[tc][r] * scale2;
            if (tc*16 + quad*4 + r > qrel) s = -3.0e38f;
            sv[tc][r] = s;
            pmax = fmaxf(pmax, s);
          }
      }
      pmax = fmaxf(pmax, __shfl_xor(pmax, 16));
      pmax = fmaxf(pmax, __shfl_xor(pmax, 32));

      if (__all(pmax <= m_ln + 11.0f)) {        // T13 defer-max
        float lt = 0.f;
        #pragma unroll
        for (int tc = 0; tc < 4; tc++)
          #pragma unroll
          for (int r = 0; r < 4; r++) {
            sv[tc][r] = exp2f(sv[tc][r] - m_ln);
            lt += sv[tc][r];
          }
        lt += __shfl_xor(lt, 16);
        lt += __shfl_xor(lt, 32);
        l_ln += lt;
      } else {
        const float mnew = fmaxf(m_ln, pmax);
        float lt = 0.f;
        #pragma unroll
        for (int tc = 0; tc < 4; tc++)
          #pragma unroll
          for (int r = 0; r < 4; r++) {
            sv[tc][r] = exp2f(sv[tc][r] - mnew);
            lt += sv[tc][r];
          }
        lt += __shfl_xor(lt, 16);
        lt += __shfl_xor(lt, 32);
        const float al = exp2f(m_ln - mnew);
        l_ln = l_ln * al + lt;
        m_ln = mnew;
        float alr[4];
        #pragma unroll
        for (int r = 0; r < 4; r++) alr[r] = __shfl(al, quad*4 + r);
        #pragma unroll
        for (int t = 0; t < 8; t++)
          #pragma unroll
          for (int r = 0; r < 4; r++) O[t][r] *= alr[r];
      }

      #pragma unroll
      for (int tc = 0; tc < 4; tc++) {
        short4v pw;
        pw[0] = (short)f2bf(sv[tc][0]); pw[1] = (short)f2bf(sv[tc][1]);
        pw[2] = (short)f2bf(sv[tc][2]); pw[3] = (short)f2bf(sv[tc][3]);
        *(short4v*)&Ps[w][col*PSTR + tc*16 + quad*4] = pw;
      }

      __builtin_amdgcn_s_setprio(1);
      if (!diag) {
        #pragma unroll
        for (int ks = 0; ks < 2; ks++) {
          short8 pf = *(const short8*)&Ps[w][col*PSTR + 32*ks + quad*8];
          #pragma unroll
          for (int t = 0; t < 8; t++) {
            short8 vf = *(const short8*)&Vt[(16*t + col)*VSTR + 32*ks + quad*8];
            O[t] = __builtin_amdgcn_mfma_f32_16x16x32_bf16(pf, vf, O[t], 0,0,0);
          }
        }
      } else {
        #pragma unroll
        for (int ks = 0; ks < 2; ks++) {
          if (ks == 0 || w >= 2) {
            short8 pf = *(const short8*)&Ps[w][col*PSTR + 32*ks + quad*8];
            #pragma unroll
            for (int t = 0; t < 8; t++) {
              short8 vf = *(const short8*)&Vt[(16*t + col)*VSTR + 32*ks + quad*8];
              O[t] = __builtin_amdgcn_mfma_f32_16x16x32_bf16(pf, vf, O[t], 0,0,0);
            }
          }
        }
      }
      __builtin_amdgcn_s_setprio(0);
      __syncthreads();
    }

    float lr[4];
    #pragma unroll
    for (int r = 0; r < 4; r++) lr[r] = __shfl(l_ln, quad*4 + r);
    #pragma unroll
    for (int r = 0; r < 4; r++) {
      const float linv = 1.f / lr[r];
      const size_t mq = (size_t)b*S_ + q0w + quad*4 + r;
      bf16* dst = at + mq*HID_ + h*HD_ + col;
      #pragma unroll
      for (int t = 0; t < 8; t++)
        dst[16*t] = __float2bfloat16(O[t][r] * linv);
    }
  }
}

extern "C" void kernel_launch(void* const* d_in, const int* in_sizes, int n_in,
                              void* d_out, int out_size, void* d_ws, size_t ws_size,
                              hipStream_t stream)
{
  float* out = (float*)d_out;

  // Size guard tripwire.
  static const int sz_dict[10] = {6291456,131072,294912,294912,147456,
                                  147456,294912,1179648,147456,2359296};
  int bad = -1;
  if (n_in < 10) bad = 15;
  else {
    for (int i = 0; i < 10; i++)
      if (in_sizes[i] != sz_dict[i]) { bad = i; break; }
  }
  if (bad >= 0) {
    float v = 1.0e6f * (float)(1 + bad);
    if (bad < 10) v += (float)(in_sizes[bad] % 1000000);
    fillf_k<<<(out_size + 255)/256, 256, 0, stream>>>(out, v, out_size);
    return;
  }

  const float* hidden = (const float*)d_in[0];
  const float* emb    = (const float*)d_in[1];
  const float* Wkvd   = (const float*)d_in[2];
  const float* Wqd    = (const float*)d_in[3];
  const float* Wku    = (const float*)d_in[4];
  const float* Wqu    = (const float*)d_in[5];
  const float* Wvu    = (const float*)d_in[6];
  const float* Wrk    = (const float*)d_in[7];
  const float* Wrq    = (const float*)d_in[8];
  const float* Wo     = (const float*)d_in[9];

  // --- workspace carve (256B aligned each) ---
  char* wp = (char*)d_ws;
  size_t used = 0;
  auto alloc = [&](size_t bytes) -> void* {
    void* p = wp + used;
    used += (bytes + 255) & ~(size_t)255;
    return p;
  };
  bf16*  hb    = (bf16*)alloc((size_t)M_*HID_*2);        // hidden bf16
  bf16*  dout  = (bf16*)alloc((size_t)M_*384*2);         // [kvd|qd] (M,384)
  bf16*  Kf    = (bf16*)alloc((size_t)M_*HID_*2);        // [m][h][128] bf16
  bf16*  Qf    = (bf16*)alloc((size_t)M_*HID_*2);
  bf16*  Vtg   = (bf16*)alloc((size_t)B_*H_*HD_*S_*2);   // [b][h][d][s] bf16
  bf16*  at    = (bf16*)alloc((size_t)M_*HID_*2);
  bf16*  WdkrT = (bf16*)alloc((size_t)1152*HID_*2);      // [WkvdT;WqdT;WrkT]
  bf16*  WkvuT = (bf16*)alloc((size_t)2304*LAT_*2);      // [WkuT;WvuT]
  bf16*  WqurT = (bf16*)alloc((size_t)1536*LAT_*2);      // [WquT;WrqT]
  bf16*  WoT   = (bf16*)alloc((size_t)HID_*HID_*2);
  int*   qcnt  = (int*)alloc(256);

  if (used > ws_size) {   // workspace tripwire
    fillf_k<<<(out_size + 255)/256, 256, 0, stream>>>(out, 5.0e7f, out_size);
    return;
  }

  hipMemsetAsync(qcnt, 0, sizeof(int), stream);

  // --- weight packs (2 launches; z=4 of the first is packA of hidden) ---
  packT5_k<<<dim3(48,48,5), 256, 0, stream>>>(
      Wkvd, Wqd, Wrk, Wo,
      WdkrT, WdkrT + (size_t)192*HID_, WdkrT + (size_t)384*HID_, WoT,
      HID_, LAT_, LAT_, H_*ROT_, HID_,
      hidden, hb);
  packT5_k<<<dim3(6,48,4), 256, 0, stream>>>(
      Wku, Wvu, Wqu, Wrq,
      WkvuT, WkvuT + (size_t)768*LAT_, WqurT, WqurT + (size_t)768*LAT_,
      LAT_, H_*ROT_, HID_, H_*ROT_, H_*ROT_,
      nullptr, nullptr);

  // --- fused MFMA GEMMs ---
  // G1: hb @ [Wkvd;Wqd;Wrk]^T -> dout | rope-K into Kf[64..127]
  gemm_mfma<5,128><<<dim3(9, M_/128), 256, 0, stream>>>(
      hb, WdkrT, nullptr, nullptr, dout, Kf, nullptr, emb, HID_, HID_, HID_, 0);
  // G23: [dout|qd] @ [Wku;Wvu | Wqu;Wrq]^T -> k_c->Kf, V->Vtg, q_c->Qf, ropeQ->Qf
  gemm_mfma<6,128><<<dim3(30, M_/128), 256, 0, stream>>>(
      dout, WkvuT, dout + 192, WqurT, Kf, Vtg, Qf, emb, LAT_, 384, LAT_, 0);

  // MFMA flash attention (dynamic heavy-first queue, grid 512)
  attn_mfma<<<512, 256, 0, stream>>>(Qf, Kf, Vtg, at, qcnt);

  // out = at @ Wo
  gemm_mfma<0,128><<<dim3(HID_/128, M_/128), 256, 0, stream>>>(
      at, WoT, nullptr, nullptr, out, nullptr, nullptr, emb, HID_, HID_, HID_, HID_);
}

// Round 6
// 240.075 us; speedup vs baseline: 5.0520x; 1.0910x over previous
//
#include <hip/hip_runtime.h>
#include <hip/hip_bf16.h>

#define B_ 2
#define S_ 2048
#define HID_ 1536
#define H_ 12
#define HD_ 128
#define LAT_ 192
#define ROT_ 64
#define M_ (B_*S_)         // 4096
#define NTILE_ (B_*H_*(S_/64))   // 768 attn q-tiles

typedef __hip_bfloat16 bf16;

using short8  = __attribute__((ext_vector_type(8))) short;
using short4v = __attribute__((ext_vector_type(4))) short;
using float4v = __attribute__((ext_vector_type(4))) float;

__device__ __forceinline__ unsigned short f2bf(float f) {
  __hip_bfloat16 h = __float2bfloat16(f);
  unsigned short u; __builtin_memcpy(&u, &h, 2); return u;
}

// async global->LDS, 16B per lane (wave-uniform LDS base + lane*16)
#define GLDS16(gp, lp) __builtin_amdgcn_global_load_lds( \
    (__attribute__((address_space(1))) void*)(size_t)(gp), \
    (__attribute__((address_space(3))) void*)(lp), 16, 0, 0)

__global__ __launch_bounds__(256)
void fillf_k(float* __restrict__ out, float v, int n)
{
  int i = blockIdx.x*256 + threadIdx.x;
  if (i < n) out[i] = v;
}

// ---------------------------------------------------------------------------
// Batched weight transpose+pack (z=0..3): W(K,N) fp32 -> Wt(N,K) bf16.
// z=4: grid-stride fp32->bf16 elementwise pack of hidden (packA).
// ---------------------------------------------------------------------------
__global__ __launch_bounds__(256)
void packT5_k(const float* __restrict__ s0, const float* __restrict__ s1,
              const float* __restrict__ s2, const float* __restrict__ s3,
              bf16* __restrict__ d0, bf16* __restrict__ d1,
              bf16* __restrict__ d2, bf16* __restrict__ d3,
              int Kn, int N0, int N1, int N2, int N3,
              const float* __restrict__ hsrc, bf16* __restrict__ hdst)
{
  if (blockIdx.z == 4) {               // packA branch (grid-stride float4)
    const int nblk = gridDim.x * gridDim.y;
    const int flatb = blockIdx.y * gridDim.x + blockIdx.x;
    const float4* in4 = (const float4*)hsrc;
    for (int i = flatb*256 + threadIdx.x; i < M_*HID_/4; i += nblk*256) {
      float4 v = in4[i];
      short4v o;
      o[0] = (short)f2bf(v.x); o[1] = (short)f2bf(v.y);
      o[2] = (short)f2bf(v.z); o[3] = (short)f2bf(v.w);
      *(short4v*)&hdst[i*4] = o;
    }
    return;
  }
  const float* W; bf16* Wt; int Nn;
  switch (blockIdx.z) {
    case 0:  W = s0; Wt = d0; Nn = N0; break;
    case 1:  W = s1; Wt = d1; Nn = N1; break;
    case 2:  W = s2; Wt = d2; Nn = N2; break;
    default: W = s3; Wt = d3; Nn = N3; break;
  }
  const int kb = blockIdx.x*32, nb = blockIdx.y*32;
  if (nb >= Nn) return;
  __shared__ float t[32][33];
  const int tx = threadIdx.x & 31, ty = threadIdx.x >> 5;
  #pragma unroll
  for (int i = 0; i < 4; i++)
    t[ty+8*i][tx] = W[(size_t)(kb+ty+8*i)*Nn + nb + tx];
  __syncthreads();
  #pragma unroll
  for (int i = 0; i < 4; i++)
    Wt[(size_t)(nb + ty + 8*i)*Kn + kb + tx] = __float2bfloat16(t[tx][ty+8*i]);
}

// ---------------------------------------------------------------------------
// MFMA bf16 GEMM: C(M,N) = A(M,K) @ Bt(N,K)^T.  BM x 128 tile, BK=64,
// 4 waves 2x2, each wave (BM/2)x64.  LDS staged via global_load_lds with
// XOR-swizzled GLOBAL source (T2 both-sides rule).
// CMODE epilogues (regions block-uniform; boundaries on 128 multiples):
//   0: fp32 linear (ldc)                                 [out = at @ Wo]
//   5: c<384 -> dout bf16 (ldc 384); else ROPE -> Kf dims 64..127
//   6: c<768 -> Kf k_c head-split; <2304 -> V transposed -> Vtg;
//      <3072 -> Qf q_c head-split; else ROPE -> Qf dims 64..127
//      (CMODE 6 selects A/B base by n0: >=2304 uses Av2/Bt2, rows n0-2304)
// Rope pairing is lane-local: acc[i][j] (d=j*16+col<32) pairs acc[i][j+2].
// ---------------------------------------------------------------------------
template<int CMODE, int BM>
__global__ __launch_bounds__(256)
void gemm_mfma(const bf16* __restrict__ Av, const bf16* __restrict__ Btp,
               const bf16* __restrict__ Av2, const bf16* __restrict__ Bt2,
               void* __restrict__ Cv, void* __restrict__ Cv2,
               void* __restrict__ Cv3,
               const float* __restrict__ emb, int Kn, int lda, int ldb, int ldc)
{
  constexpr int MI  = BM/32;         // 16-row tiles per wave
  constexpr int ITA = BM/32;         // A GLDS staging calls
  __shared__ bf16 As[(size_t)BM*64];
  __shared__ bf16 Bs[128*64];

  const int tid  = threadIdx.x;
  const int lane = tid & 63;
  const int w    = tid >> 6;
  const int col  = lane & 15, quad = lane >> 4;
  const int wr   = w >> 1, wc = w & 1;
  const size_t m0 = (size_t)blockIdx.y * BM;
  const size_t n0 = (size_t)blockIdx.x * 128;

  const bf16* Abase = Av;
  const bf16* Bt    = Btp;
  size_t nrow0 = n0;
  if constexpr (CMODE == 6) {
    if ((int)n0 >= 2304) { Abase = Av2; Bt = Bt2; nrow0 = n0 - 2304; }
  }

  const bf16* bg[4];
  #pragma unroll
  for (int it = 0; it < 4; it++) {
    int c = tid + it*256, row = c >> 3, seg = c & 7;
    bg[it] = Bt + (nrow0 + row)*ldb + (size_t)((seg ^ (row & 7))*8);
  }
  const bf16* ag[ITA];
  #pragma unroll
  for (int it = 0; it < ITA; it++) {
    int c = tid + it*256, row = c >> 3, seg = c & 7;
    ag[it] = Abase + (m0 + row)*lda + (size_t)((seg ^ (row & 7))*8);
  }

  float4v acc[MI][4];
  #pragma unroll
  for (int i=0;i<MI;i++)
    #pragma unroll
    for (int j=0;j<4;j++) acc[i][j] = (float4v){0.f,0.f,0.f,0.f};

  for (int k0 = 0; k0 < Kn; k0 += 64) {
    #pragma unroll
    for (int it = 0; it < 4; it++)
      GLDS16(bg[it] + k0, Bs + (size_t)(tid + it*256)*8);
    #pragma unroll
    for (int it = 0; it < ITA; it++)
      GLDS16(ag[it] + k0, As + (size_t)(tid + it*256)*8);
    __syncthreads();

    short8 af[MI][2], bfr[4][2];
    #pragma unroll
    for (int i=0;i<MI;i++) {
      const int ar = wr*(BM/2) + i*16 + col;
      #pragma unroll
      for (int k2=0;k2<2;k2++)
        af[i][k2] = *(const short8*)&As[ar*64 + ((k2*4+quad)^(ar&7))*8];
    }
    #pragma unroll
    for (int j=0;j<4;j++) {
      const int br = wc*64 + j*16 + col;
      #pragma unroll
      for (int k2=0;k2<2;k2++)
        bfr[j][k2] = *(const short8*)&Bs[br*64 + ((k2*4+quad)^(br&7))*8];
    }

    #pragma unroll
    for (int k2=0;k2<2;k2++)
      #pragma unroll
      for (int i=0;i<MI;i++)
        #pragma unroll
        for (int j=0;j<4;j++)
          acc[i][j] = __builtin_amdgcn_mfma_f32_16x16x32_bf16(af[i][k2], bfr[j][k2], acc[i][j], 0,0,0);
    __syncthreads();
  }

  // ---- epilogues ----
  if constexpr (CMODE == 0) {
    #pragma unroll
    for (int i=0;i<MI;i++) {
      const size_t row0 = m0 + wr*(BM/2) + i*16 + quad*4;
      #pragma unroll
      for (int j=0;j<4;j++) {
        const int c = (int)n0 + wc*64 + j*16 + col;
        #pragma unroll
        for (int r=0;r<4;r++)
          ((float*)Cv)[(row0+r)*ldc + c] = acc[i][j][r];
      }
    }
    return;
  }

  if constexpr (CMODE == 5) {
    if ((int)n0 < 384) {
      #pragma unroll
      for (int i=0;i<MI;i++) {
        const size_t row0 = m0 + wr*(BM/2) + i*16 + quad*4;
        #pragma unroll
        for (int j=0;j<4;j++) {
          const int c = (int)n0 + wc*64 + j*16 + col;
          #pragma unroll
          for (int r=0;r<4;r++)
            ((bf16*)Cv)[(row0+r)*384 + c] = __float2bfloat16(acc[i][j][r]);
        }
      }
    } else {
      // rope -> Kf dims 64..127
      const int hh = (((int)n0 - 384) >> 6) + wc;
      #pragma unroll
      for (int i=0;i<MI;i++) {
        const size_t row0 = m0 + wr*(BM/2) + i*16 + quad*4;
        #pragma unroll
        for (int j=0;j<2;j++) {
          const int idim = j*16 + col;
          #pragma unroll
          for (int r=0;r<4;r++) {
            const size_t row = row0 + r;
            const int s = (int)(row & (S_-1));
            const float sn = emb[(size_t)s*ROT_ + idim];
            const float cs = emb[(size_t)s*ROT_ + 32 + idim];
            const float x1 = acc[i][j][r], x2 = acc[i][j+2][r];
            bf16* dst = (bf16*)Cv2 + (row*H_ + hh)*HD_ + 64 + idim;
            dst[0]  = __float2bfloat16(x1*cs - x2*sn);
            dst[32] = __float2bfloat16(x1*sn + x2*cs);
          }
        }
      }
    }
    return;
  }

  // CMODE == 6
  if ((int)n0 < 768) {
    // k_c head-split into Kf dims 0..63
    #pragma unroll
    for (int i=0;i<MI;i++) {
      const size_t row0 = m0 + wr*(BM/2) + i*16 + quad*4;
      #pragma unroll
      for (int j=0;j<4;j++) {
        const int c = (int)n0 + wc*64 + j*16 + col;
        #pragma unroll
        for (int r=0;r<4;r++)
          ((bf16*)Cv)[(row0+r)*HID_ + (c>>6)*HD_ + (c&63)] = __float2bfloat16(acc[i][j][r]);
      }
    }
  } else if ((int)n0 < 2304) {
    // V transposed into Vtg[b][h][d][s]; 4 rows s-contiguous -> short4
    #pragma unroll
    for (int i=0;i<MI;i++) {
      const size_t row0 = m0 + wr*(BM/2) + i*16 + quad*4;
      const int bb = (int)(row0 >> 11), s = (int)(row0 & (S_-1));
      #pragma unroll
      for (int j=0;j<4;j++) {
        const int cv = (int)n0 - 768 + wc*64 + j*16 + col;
        const int hh = cv >> 7, d = cv & 127;
        short4v st;
        #pragma unroll
        for (int r=0;r<4;r++) st[r] = (short)f2bf(acc[i][j][r]);
        *(short4v*)((unsigned short*)Cv2 +
            ((size_t)(bb*H_+hh)*HD_ + d)*S_ + s) = st;
      }
    }
  } else if ((int)n0 < 3072) {
    // q_c head-split into Qf dims 0..63
    #pragma unroll
    for (int i=0;i<MI;i++) {
      const size_t row0 = m0 + wr*(BM/2) + i*16 + quad*4;
      #pragma unroll
      for (int j=0;j<4;j++) {
        const int c = (int)n0 - 2304 + wc*64 + j*16 + col;
        #pragma unroll
        for (int r=0;r<4;r++)
          ((bf16*)Cv3)[(row0+r)*HID_ + (c>>6)*HD_ + (c&63)] = __float2bfloat16(acc[i][j][r]);
      }
    }
  } else {
    // rope -> Qf dims 64..127
    const int hh = (((int)n0 - 3072) >> 6) + wc;
    #pragma unroll
    for (int i=0;i<MI;i++) {
      const size_t row0 = m0 + wr*(BM/2) + i*16 + quad*4;
      #pragma unroll
      for (int j=0;j<2;j++) {
        const int idim = j*16 + col;
        #pragma unroll
        for (int r=0;r<4;r++) {
          const size_t row = row0 + r;
          const int s = (int)(row & (S_-1));
          const float sn = emb[(size_t)s*ROT_ + idim];
          const float cs = emb[(size_t)s*ROT_ + 32 + idim];
          const float x1 = acc[i][j][r], x2 = acc[i][j+2][r];
          bf16* dst = (bf16*)Cv3 + (row*H_ + hh)*HD_ + 64 + idim;
          dst[0]  = __float2bfloat16(x1*cs - x2*sn);
          dst[32] = __float2bfloat16(x1*sn + x2*cs);
        }
      }
    }
  }
}

// ---------------------------------------------------------------------------
// MFMA flash attention, causal. 4 waves = 64 queries/tile; 64-key blocks.
// STATIC BALANCED schedule: CU i holds blocks {i, i+256, i+512} (XCD
// round-robin + per-XCD fill).  Position p -> weight-rank r via
// {p, 511-p, 512+p} chunking -> per-CU triple weight sums 45..54 (was
// 32..64 with plain desc order).  Rank order stays qt-major, so same-bh
// tiles remain 24 apart -> same XCD -> L2-resident K/V (R5's dynamic
// queue broke this: FETCH 18.6->110 MB, dur +10us.  Reverted).
// Swapped QK^T, T14 reg prefetch, bulk/diag split, defer-max, exp2 domain.
// ---------------------------------------------------------------------------
#define KSTR 136   // 128+8  (272B rows, 16B aligned)
#define VSTR 72    // 64+8   (144B rows, 16B aligned)
#define PSTR 72

__global__ __launch_bounds__(256)
void attn_mfma(const bf16* __restrict__ Qf, const bf16* __restrict__ Kf,
               const bf16* __restrict__ Vtg, bf16* __restrict__ at)
{
  const int p     = (int)blockIdx.x;
  const int ii    = p & 255;
  const int third = p >> 8;
  const int rank  = (third == 0) ? ii : (third == 1 ? 511 - ii : 512 + ii);
  const int qt = (S_/64 - 1) - rank/24;       // weight-desc rank -> qt
  const int bh = rank % 24;
  const int h  = bh % H_, b = bh / H_;

  const int tid  = threadIdx.x;
  const int w    = tid >> 6;
  const int lane = tid & 63;
  const int col  = lane & 15;
  const int quad = lane >> 4;

  __shared__ unsigned short Ks[64*KSTR];       // 17408 B
  __shared__ unsigned short Vt[128*VSTR];      // 18432 B
  __shared__ unsigned short Ps[4][16*PSTR];    //  9216 B

  const int q0w = qt*64 + w*16;

  const unsigned short* Kb = (const unsigned short*)Kf +
      ((size_t)b*S_*H_ + h)*HD_;
  const unsigned short* Vb = (const unsigned short*)Vtg +
      (size_t)(b*H_ + h)*HD_*S_;

  const unsigned short* kgp[4]; unsigned short* kdst[4];
  const unsigned short* vgp[4]; unsigned short* vdst[4];
  #pragma unroll
  for (int it = 0; it < 4; it++) {
    int c = tid + it*256;
    int key = c >> 4, doff = (c & 15)*8;
    kgp[it]  = Kb + (size_t)key*HID_ + doff;
    kdst[it] = &Ks[key*KSTR + doff];
    int d = c >> 3, kg = (c & 7)*8;
    vgp[it]  = Vb + (size_t)d*S_ + kg;
    vdst[it] = &Vt[d*VSTR + kg];
  }

  // Q fragments (B-operand of swapped QK^T)
  short8 qf[4];
  {
    const unsigned short* qrow = (const unsigned short*)Qf +
        ((size_t)((size_t)b*S_ + q0w + col)*H_ + h)*HD_;
    #pragma unroll
    for (int kk = 0; kk < 4; kk++)
      qf[kk] = *(const short8*)(qrow + kk*32 + quad*8);
  }

  float4v O[8];
  #pragma unroll
  for (int t=0;t<8;t++) O[t] = (float4v){0.f,0.f,0.f,0.f};
  float m_ln = -1e30f, l_ln = 0.f;

  const float scale2 = 0.08838834764831845f * 1.4426950408889634f;

  short8 kr[4], vr[4];
  #pragma unroll
  for (int it = 0; it < 4; it++) {
    kr[it] = *(const short8*)kgp[it];
    vr[it] = *(const short8*)vgp[it];
  }

  for (int kb = 0; kb <= qt; kb++) {
    const int k0 = kb * 64;
    const bool diag = (kb == qt);

    #pragma unroll
    for (int it = 0; it < 4; it++) *(short8*)kdst[it] = kr[it];
    #pragma unroll
    for (int it = 0; it < 4; it++) *(short8*)vdst[it] = vr[it];
    __syncthreads();

    if (!diag) {   // T14 prefetch
      const size_t kn = (size_t)(k0 + 64);
      #pragma unroll
      for (int it = 0; it < 4; it++) {
        kr[it] = *(const short8*)(kgp[it] + kn*HID_);
        vr[it] = *(const short8*)(vgp[it] + kn);
      }
    }

    float4v Sf[4];
    #pragma unroll
    for (int tc=0;tc<4;tc++) Sf[tc] = (float4v){0.f,0.f,0.f,0.f};
    __builtin_amdgcn_s_setprio(1);
    if (!diag) {
      #pragma unroll
      for (int tc = 0; tc < 4; tc++)
        #pragma unroll
        for (int kk = 0; kk < 4; kk++) {
          short8 kfrag = *(const short8*)&Ks[(16*tc+col)*KSTR + 32*kk + quad*8];
          Sf[tc] = __builtin_amdgcn_mfma_f32_16x16x32_bf16(kfrag, qf[kk], Sf[tc], 0,0,0);
        }
    } else {
      #pragma unroll
      for (int tc = 0; tc < 4; tc++) {
        if (tc <= w) {
          #pragma unroll
          for (int kk = 0; kk < 4; kk++) {
            short8 kfrag = *(const short8*)&Ks[(16*tc+col)*KSTR + 32*kk + quad*8];
            Sf[tc] = __builtin_amdgcn_mfma_f32_16x16x32_bf16(kfrag, qf[kk], Sf[tc], 0,0,0);
          }
        }
      }
    }
    __builtin_amdgcn_s_setprio(0);

    float sv[4][4];
    float pmax = -3.0e38f;
    if (!diag) {
      #pragma unroll
      for (int tc = 0; tc < 4; tc++)
        #pragma unroll
        for (int r = 0; r < 4; r++) {
          float s = Sf[tc][r] * scale2;
          sv[tc][r] = s;
          pmax = fmaxf(pmax, s);
        }
    } else {
      const int qrel = w*16 + col;
      #pragma unroll
      for (int tc = 0; tc < 4; tc++)
        #pragma unroll
        for (int r = 0; r < 4; r++) {
          float s = Sf[tc][r] * scale2;
          if (tc*16 + quad*4 + r > qrel) s = -3.0e38f;
          sv[tc][r] = s;
          pmax = fmaxf(pmax, s);
        }
    }
    pmax = fmaxf(pmax, __shfl_xor(pmax, 16));
    pmax = fmaxf(pmax, __shfl_xor(pmax, 32));

    if (__all(pmax <= m_ln + 11.0f)) {        // T13 defer-max
      float lt = 0.f;
      #pragma unroll
      for (int tc = 0; tc < 4; tc++)
        #pragma unroll
        for (int r = 0; r < 4; r++) {
          sv[tc][r] = exp2f(sv[tc][r] - m_ln);
          lt += sv[tc][r];
        }
      lt += __shfl_xor(lt, 16);
      lt += __shfl_xor(lt, 32);
      l_ln += lt;
    } else {
      const float mnew = fmaxf(m_ln, pmax);
      float lt = 0.f;
      #pragma unroll
      for (int tc = 0; tc < 4; tc++)
        #pragma unroll
        for (int r = 0; r < 4; r++) {
          sv[tc][r] = exp2f(sv[tc][r] - mnew);
          lt += sv[tc][r];
        }
      lt += __shfl_xor(lt, 16);
      lt += __shfl_xor(lt, 32);
      const float al = exp2f(m_ln - mnew);
      l_ln = l_ln * al + lt;
      m_ln = mnew;
      float alr[4];
      #pragma unroll
      for (int r = 0; r < 4; r++) alr[r] = __shfl(al, quad*4 + r);
      #pragma unroll
      for (int t = 0; t < 8; t++)
        #pragma unroll
        for (int r = 0; r < 4; r++) O[t][r] *= alr[r];
    }

    #pragma unroll
    for (int tc = 0; tc < 4; tc++) {
      short4v pw;
      pw[0] = (short)f2bf(sv[tc][0]); pw[1] = (short)f2bf(sv[tc][1]);
      pw[2] = (short)f2bf(sv[tc][2]); pw[3] = (short)f2bf(sv[tc][3]);
      *(short4v*)&Ps[w][col*PSTR + tc*16 + quad*4] = pw;
    }

    __builtin_amdgcn_s_setprio(1);
    if (!diag) {
      #pragma unroll
      for (int ks = 0; ks < 2; ks++) {
        short8 pf = *(const short8*)&Ps[w][col*PSTR + 32*ks + quad*8];
        #pragma unroll
        for (int t = 0; t < 8; t++) {
          short8 vf = *(const short8*)&Vt[(16*t + col)*VSTR + 32*ks + quad*8];
          O[t] = __builtin_amdgcn_mfma_f32_16x16x32_bf16(pf, vf, O[t], 0,0,0);
        }
      }
    } else {
      #pragma unroll
      for (int ks = 0; ks < 2; ks++) {
        if (ks == 0 || w >= 2) {
          short8 pf = *(const short8*)&Ps[w][col*PSTR + 32*ks + quad*8];
          #pragma unroll
          for (int t = 0; t < 8; t++) {
            short8 vf = *(const short8*)&Vt[(16*t + col)*VSTR + 32*ks + quad*8];
            O[t] = __builtin_amdgcn_mfma_f32_16x16x32_bf16(pf, vf, O[t], 0,0,0);
          }
        }
      }
    }
    __builtin_amdgcn_s_setprio(0);
    __syncthreads();
  }

  float lr[4];
  #pragma unroll
  for (int r = 0; r < 4; r++) lr[r] = __shfl(l_ln, quad*4 + r);
  #pragma unroll
  for (int r = 0; r < 4; r++) {
    const float linv = 1.f / lr[r];
    const size_t mq = (size_t)b*S_ + q0w + quad*4 + r;
    bf16* dst = at + mq*HID_ + h*HD_ + col;
    #pragma unroll
    for (int t = 0; t < 8; t++)
      dst[16*t] = __float2bfloat16(O[t][r] * linv);
  }
}

extern "C" void kernel_launch(void* const* d_in, const int* in_sizes, int n_in,
                              void* d_out, int out_size, void* d_ws, size_t ws_size,
                              hipStream_t stream)
{
  float* out = (float*)d_out;

  // Size guard tripwire.
  static const int sz_dict[10] = {6291456,131072,294912,294912,147456,
                                  147456,294912,1179648,147456,2359296};
  int bad = -1;
  if (n_in < 10) bad = 15;
  else {
    for (int i = 0; i < 10; i++)
      if (in_sizes[i] != sz_dict[i]) { bad = i; break; }
  }
  if (bad >= 0) {
    float v = 1.0e6f * (float)(1 + bad);
    if (bad < 10) v += (float)(in_sizes[bad] % 1000000);
    fillf_k<<<(out_size + 255)/256, 256, 0, stream>>>(out, v, out_size);
    return;
  }

  const float* hidden = (const float*)d_in[0];
  const float* emb    = (const float*)d_in[1];
  const float* Wkvd   = (const float*)d_in[2];
  const float* Wqd    = (const float*)d_in[3];
  const float* Wku    = (const float*)d_in[4];
  const float* Wqu    = (const float*)d_in[5];
  const float* Wvu    = (const float*)d_in[6];
  const float* Wrk    = (const float*)d_in[7];
  const float* Wrq    = (const float*)d_in[8];
  const float* Wo     = (const float*)d_in[9];

  // --- workspace carve (256B aligned each) ---
  char* wp = (char*)d_ws;
  size_t used = 0;
  auto alloc = [&](size_t bytes) -> void* {
    void* p = wp + used;
    used += (bytes + 255) & ~(size_t)255;
    return p;
  };
  bf16*  hb    = (bf16*)alloc((size_t)M_*HID_*2);        // hidden bf16
  bf16*  dout  = (bf16*)alloc((size_t)M_*384*2);         // [kvd|qd] (M,384)
  bf16*  Kf    = (bf16*)alloc((size_t)M_*HID_*2);        // [m][h][128] bf16
  bf16*  Qf    = (bf16*)alloc((size_t)M_*HID_*2);
  bf16*  Vtg   = (bf16*)alloc((size_t)B_*H_*HD_*S_*2);   // [b][h][d][s] bf16
  bf16*  at    = (bf16*)alloc((size_t)M_*HID_*2);
  bf16*  WdkrT = (bf16*)alloc((size_t)1152*HID_*2);      // [WkvdT;WqdT;WrkT]
  bf16*  WkvuT = (bf16*)alloc((size_t)2304*LAT_*2);      // [WkuT;WvuT]
  bf16*  WqurT = (bf16*)alloc((size_t)1536*LAT_*2);      // [WquT;WrqT]
  bf16*  WoT   = (bf16*)alloc((size_t)HID_*HID_*2);

  if (used > ws_size) {   // workspace tripwire
    fillf_k<<<(out_size + 255)/256, 256, 0, stream>>>(out, 5.0e7f, out_size);
    return;
  }

  // --- weight packs (2 launches; z=4 of the first is packA of hidden) ---
  packT5_k<<<dim3(48,48,5), 256, 0, stream>>>(
      Wkvd, Wqd, Wrk, Wo,
      WdkrT, WdkrT + (size_t)192*HID_, WdkrT + (size_t)384*HID_, WoT,
      HID_, LAT_, LAT_, H_*ROT_, HID_,
      hidden, hb);
  packT5_k<<<dim3(6,48,4), 256, 0, stream>>>(
      Wku, Wvu, Wqu, Wrq,
      WkvuT, WkvuT + (size_t)768*LAT_, WqurT, WqurT + (size_t)768*LAT_,
      LAT_, H_*ROT_, HID_, H_*ROT_, H_*ROT_,
      nullptr, nullptr);

  // --- fused MFMA GEMMs ---
  // G1: hb @ [Wkvd;Wqd;Wrk]^T -> dout | rope-K into Kf[64..127]
  //     BM=64: grid 576 blocks (BM=128 gave only 288 -> CUs underfilled)
  gemm_mfma<5,64><<<dim3(9, M_/64), 256, 0, stream>>>(
      hb, WdkrT, nullptr, nullptr, dout, Kf, nullptr, emb, HID_, HID_, HID_, 0);
  // G23: [dout|qd] @ [Wku;Wvu | Wqu;Wrq]^T -> k_c->Kf, V->Vtg, q_c->Qf, ropeQ->Qf
  gemm_mfma<6,128><<<dim3(30, M_/128), 256, 0, stream>>>(
      dout, WkvuT, dout + 192, WqurT, Kf, Vtg, Qf, emb, LAT_, 384, LAT_, 0);

  // MFMA flash attention (static balanced schedule, grid 768)
  attn_mfma<<<NTILE_, 256, 0, stream>>>(Qf, Kf, Vtg, at);

  // G4: out = at @ Wo   (BM=64: grid 768 blocks for full CU coverage)
  gemm_mfma<0,64><<<dim3(HID_/64 /*=24 N-tiles? no: N=1536/128=12*/ * 0 + 12, M_/64), 256, 0, stream>>>(
      at, WoT, nullptr, nullptr, out, nullptr, nullptr, emb, HID_, HID_, HID_, HID_);
}